// Round 17
// baseline (134.182 us; speedup 1.0000x reference)
//
#include <hip/hip_runtime.h>
#include <hip/hip_bf16.h>
#include <stdint.h>

typedef __attribute__((ext_vector_type(8))) short bf16x8;
typedef __attribute__((ext_vector_type(4))) float f32x4;
typedef __attribute__((ext_vector_type(8))) unsigned short u16x8;
typedef __attribute__((ext_vector_type(4))) unsigned short u16x4;
typedef __attribute__((ext_vector_type(2))) unsigned long long ull2;

#define B_ 2
#define S_ 2048
#define E_ 2048
#define H_ 16
#define M_ 2048
#define D_ 128

#define MFMA16(a, b, c) __builtin_amdgcn_mfma_f32_16x16x32_bf16(a, b, c, 0, 0, 0)
#define MFMA8(a, b, c) __builtin_amdgcn_mfma_f32_16x16x32_fp8_fp8(a, b, c, 0, 0, 0)

__device__ inline unsigned short f2bf(float f) {
  union { float f; unsigned u; } v; v.f = f;
  unsigned r = v.u + 0x7FFFu + ((v.u >> 16) & 1u);
  return (unsigned short)(r >> 16);
}
__device__ inline float bf2f(unsigned short h) {
  union { unsigned u; float f; } v; v.u = ((unsigned)h) << 16;
  return v.f;
}

// f32 -> e4m3 single byte via HW converter (branch-free; verified r12-r15)
__device__ inline unsigned char f2e8(float f) {
  return (unsigned char)(__builtin_amdgcn_cvt_pk_fp8_f32(f, f, 0, false) & 0xFF);
}
// 4 floats -> 4 packed e4m3 bytes (verified pattern from attn P-pack)
__device__ inline uint32_t pk4e8(float a, float b, float c, float d) {
  uint32_t w = 0;
  w = (uint32_t)__builtin_amdgcn_cvt_pk_fp8_f32(a, b, (int)w, false);
  w = (uint32_t)__builtin_amdgcn_cvt_pk_fp8_f32(c, d, (int)w, true);
  return w;
}

// native 2^x
__device__ inline float exp2a(float x) {
  float r;
  asm("v_exp_f32 %0, %1" : "=v"(r) : "v"(x));
  return r;
}

__device__ inline void gload_lds16(const void* g, void* l) {
  __builtin_amdgcn_global_load_lds(
      (__attribute__((address_space(1))) void*)g,
      (__attribute__((address_space(3))) void*)l, 16, 0, 0);
}

__device__ inline bf16x8 pack8(float4 f0, float4 f1) {
  bf16x8 o;
  o[0] = (short)f2bf(f0.x); o[1] = (short)f2bf(f0.y);
  o[2] = (short)f2bf(f0.z); o[3] = (short)f2bf(f0.w);
  o[4] = (short)f2bf(f1.x); o[5] = (short)f2bf(f1.y);
  o[6] = (short)f2bf(f1.z); o[7] = (short)f2bf(f1.w);
  return o;
}

__device__ inline float block_sum(float v) {
  __shared__ float red[4];
  #pragma unroll
  for (int o = 32; o > 0; o >>= 1) v += __shfl_xor(v, o);
  int tid = threadIdx.x;
  if ((tid & 63) == 0) red[tid >> 6] = v;
  __syncthreads();
  return red[0] + red[1] + red[2] + red[3];
}

// pi(col) within a 128-col group: bits[6:5] <-> [4:3]  (col%8 preserved)
__device__ inline int pi_pos(int c) {
  return (c & ~127) | (((c >> 3) & 3) * 32) | (((c >> 5) & 3) * 8) | (c & 7);
}

// ---------------- f32 -> fp8 pi-permuted convert (wq) ----------------
__global__ __launch_bounds__(256) void f32_to_fp8_kernel(
    const float* __restrict__ in, unsigned char* __restrict__ out, int n8)
{
  int i = blockIdx.x * 256 + threadIdx.x;
  if (i >= n8) return;
  const float* p = in + (size_t)i * 8;
  float4 a = *(const float4*)p, b = *(const float4*)(p + 4);
  uint2 pk;
  pk.x = pk4e8(a.x, a.y, a.z, a.w);
  pk.y = pk4e8(b.x, b.y, b.z, b.w);
  size_t flat = (size_t)i * 8;
  int c = (int)(flat & (E_ - 1));        // col within K=2048 row
  *(uint2*)(out + (flat - c) + pi_pos(c)) = pk;
}

// ---------------- RMSNorm(query) -> fp8 qn (pi-permuted) ----------------
__global__ __launch_bounds__(256) void rmsnorm_q_kernel(
    const float* __restrict__ x, const float* __restrict__ w,
    unsigned char* __restrict__ y)
{
  const int row = blockIdx.x;
  const int tid = threadIdx.x;
  const float* xr = x + (size_t)row * E_;
  float4 v0 = ((const float4*)xr)[tid * 2];
  float4 v1 = ((const float4*)xr)[tid * 2 + 1];
  float ss = v0.x*v0.x + v0.y*v0.y + v0.z*v0.z + v0.w*v0.w
           + v1.x*v1.x + v1.y*v1.y + v1.z*v1.z + v1.w*v1.w;
  float tot = block_sum(ss);
  float sc = rsqrtf(tot * (1.0f / E_) + 1e-5f);
  float vals[8] = {v0.x, v0.y, v0.z, v0.w, v1.x, v1.y, v1.z, v1.w};
  const float* wr = w + tid * 8;
  float f[8];
  #pragma unroll
  for (int j = 0; j < 8; ++j) f[j] = vals[j] * sc * wr[j];
  uint2 pk;
  pk.x = pk4e8(f[0], f[1], f[2], f[3]);
  pk.y = pk4e8(f[4], f[5], f[6], f[7]);
  *(uint2*)(y + (size_t)row * E_ + pi_pos(tid * 8)) = pk;
}

// ---------------- GEMM C[M,N] = A[M,K] @ B[N,K]^T (fp8 in, fp8 out) ----------------
// BK=128, 128B pi-permuted rows; staging pre-swizzles source with (row&7)<<4;
// fragments are 2 x b128 per row. A/B share the pi layout -> k-pairing exact.
__global__ __launch_bounds__(256) void gemm_qproj(
    const unsigned char* __restrict__ A, const unsigned char* __restrict__ B,
    unsigned char* __restrict__ C, int M, int N, int K)
{
  __shared__ __align__(16) unsigned char As[128 * 128];  // 16KB
  __shared__ __align__(16) unsigned char Bs[128 * 128];  // 16KB
  const int nwg = gridDim.x;
  const int cpx = nwg >> 3;
  const int swz = (blockIdx.x & 7) * cpx + (blockIdx.x >> 3);
  const int mt = M >> 7;
  const int bm = (swz % mt) * 128;
  const int bn = (swz / mt) * 128;
  const int tid = threadIdx.x;
  const int wave = tid >> 6, lane = tid & 63;
  const int r = lane & 15, g = lane >> 4;
  const int wm = (wave >> 1) * 64, wn = (wave & 1) * 64;
  const int fx = (r & 7) << 4;

  f32x4 acc[4][4] = {};

  for (int k0 = 0; k0 < K; k0 += 128) {
    #pragma unroll
    for (int c = 0; c < 4; ++c) {
      int chunk = wave * 4 + c;             // 16 x 1KB chunks per 16KB tile
      int off = chunk * 1024 + lane * 16;
      int row = off >> 7;                   // 128B rows
      int cb = (off & 127) ^ ((row & 7) << 4);
      gload_lds16(A + (size_t)(bm + row) * K + k0 + cb, (char*)As + chunk * 1024);
      gload_lds16(B + (size_t)(bn + row) * K + k0 + cb, (char*)Bs + chunk * 1024);
    }
    __syncthreads();
    #pragma unroll
    for (int half = 0; half < 2; ++half) {
      ull2 af[4], bf[4];
      #pragma unroll
      for (int m = 0; m < 4; ++m)
        af[m] = *(const ull2*)((const char*)As + (wm + m * 16 + r) * 128
                               + ((g * 32 + half * 16) ^ fx));
      #pragma unroll
      for (int n = 0; n < 4; ++n)
        bf[n] = *(const ull2*)((const char*)Bs + (wn + n * 16 + r) * 128
                               + ((g * 32 + half * 16) ^ fx));
      #pragma unroll
      for (int m = 0; m < 4; ++m)
        #pragma unroll
        for (int n = 0; n < 4; ++n) {
          acc[m][n] = MFMA8((long long)af[m][0], (long long)bf[n][0], acc[m][n]);
          acc[m][n] = MFMA8((long long)af[m][1], (long long)bf[n][1], acc[m][n]);
        }
    }
    __syncthreads();
  }
  #pragma unroll
  for (int m = 0; m < 4; ++m)
    #pragma unroll
    for (int n = 0; n < 4; ++n)
      #pragma unroll
      for (int i = 0; i < 4; ++i) {
        int row = bm + wm + m * 16 + g * 4 + i;
        int col = bn + wn + n * 16 + r;
        C[(size_t)row * N + col] = f2e8(acc[m][n][i]);
      }
}

// ---------------- fused per-head K AND V projections (fp8 out, x32 encode) ----------------
// K/V^T stored with the k-dim byte-permutation pi so attention reads b128.
__global__ __launch_bounds__(256, 2) void proj_kv_kernel(
    const float* __restrict__ sp, const float* __restrict__ wk,
    const float* __restrict__ wv,
    unsigned char* __restrict__ kout, unsigned char* __restrict__ vtout)
{
  const int m0 = blockIdx.x * 64;
  const int h = blockIdx.y;
  const int tid = threadIdx.x, wave = tid >> 6, lane = tid & 63;
  const int r = lane & 15, g = lane >> 4;
  const int wm = (wave >> 1) * 32, wn = (wave & 1) * 64;
  const float* spb = sp + ((size_t)h * M_ + m0) * D_;
  f32x4 acck[2][4] = {};
  f32x4 accv[2][4] = {};
  #pragma unroll
  for (int kc = 0; kc < 4; ++kc) {
    bf16x8 a[2], bk[4], bv[4];
    #pragma unroll
    for (int m = 0; m < 2; ++m) {
      const float* p = spb + (size_t)(wm + m * 16 + r) * D_ + kc * 32 + g * 8;
      a[m] = pack8(*(const float4*)p, *(const float4*)(p + 4));
    }
    #pragma unroll
    for (int n = 0; n < 4; ++n) {
      const float* pk = wk + (size_t)(wn + n * 16 + r) * D_ + kc * 32 + g * 8;
      bk[n] = pack8(*(const float4*)pk, *(const float4*)(pk + 4));
      const float* pv = wv + (size_t)(wn + n * 16 + r) * D_ + kc * 32 + g * 8;
      bv[n] = pack8(*(const float4*)pv, *(const float4*)(pv + 4));
    }
    #pragma unroll
    for (int m = 0; m < 2; ++m)
      #pragma unroll
      for (int n = 0; n < 4; ++n) {
        acck[m][n] = MFMA16(a[m], bk[n], acck[m][n]);
        accv[m][n] = MFMA16(a[m], bv[n], accv[m][n]);
      }
  }
  #pragma unroll
  for (int m = 0; m < 2; ++m)
    #pragma unroll
    for (int n = 0; n < 4; ++n)
      #pragma unroll
      for (int i = 0; i < 4; ++i) {
        int d = wn + n * 16 + r;
        kout[((size_t)h * M_ + m0 + wm + m * 16 + g * 4 + i) * D_ + pi_pos(d)]
            = f2e8(acck[m][n][i] * 32.0f);
        int mc = m0 + wm + m * 16 + g * 4 + i;
        int mp = (mc & ~127) | (pi_pos(mc & 127));
        vtout[((size_t)h * D_ + wn + n * 16 + r) * M_ + mp]
            = f2e8(accv[m][n][i] * 32.0f);
      }
}

// ---------------- flash attention over memory slots (fp8 K/Q/V/P) ----------------
// [r14/r15 verified: 62.9-63.2us, MfmaUtil ~45, absmax 0.046875 — byte-identical]
// 8 waves x 16 q-rows; KVBLK=128; pi-permuted b128 LDS reads; swapped QK^T;
// no-max exp2 softmax; l via ones-MFMA (P-quantization bias cancels exactly).
__global__ __launch_bounds__(512, 4) void attn_kernel(
    const unsigned char* __restrict__ q,    // [B*S][E] e4m3 (plain cols)
    const unsigned char* __restrict__ kb,   // [H][M][D] e4m3 (x32, pi-permuted d)
    const unsigned char* __restrict__ vtb,  // [H][D][M] e4m3 (x32, pi-permuted m%128)
    const float* __restrict__ beta,
    unsigned short* __restrict__ ret)       // [B*S][E] bf16
{
  __shared__ __align__(16) unsigned char Ks[2][128 * 128];  // 2 x 16KB
  __shared__ __align__(16) unsigned char Vs[2][128 * 128];  // 2 x 16KB
  __shared__ __align__(16) unsigned char Ps[8][16 * 128];   // 16KB
  const int s0 = blockIdx.x * 128;
  const int h = blockIdx.y;
  const int b = blockIdx.z;
  const int tid = threadIdx.x, wave = tid >> 6, lane = tid & 63;
  const int r = lane & 15, g = lane >> 4;
  const int fx = (r & 7) << 4;
  const float escale = beta[h] * (0.08838834764831845f * 1.4426950408889634f / 32.0f);

  long long qf[4];
  {
    const unsigned char* qr0 =
        q + ((size_t)(b * S_) + s0 + wave * 16 + r) * E_ + h * D_;
    #pragma unroll
    for (int kc = 0; kc < 4; ++kc)
      qf[kc] = *(const long long*)(qr0 + kc * 32 + g * 8);
  }

  const unsigned char* Kh = kb + (size_t)h * M_ * D_;
  const unsigned char* Vh = vtb + (size_t)h * D_ * M_;
  unsigned char* Pw = Ps[wave];
  const long long ONES = 0x3838383838383838LL;  // e4m3 1.0 x8

  f32x4 o[8] = {};
  f32x4 ol = {};

  auto stage = [&](int buf, int m0) {
    #pragma unroll
    for (int c = 0; c < 2; ++c) {
      int chunk = wave * 2 + c;
      int off = chunk * 1024 + lane * 16;
      int row = off >> 7;
      int cb = (off & 127) ^ ((row & 7) << 4);
      gload_lds16(Kh + (size_t)(m0 + row) * 128 + cb, (char*)Ks[buf] + chunk * 1024);
      gload_lds16(Vh + (size_t)row * M_ + m0 + cb, (char*)Vs[buf] + chunk * 1024);
    }
  };

  stage(0, 0);
  __syncthreads();

  int cur = 0;
  for (int t = 0; t < M_ / 128; ++t) {
    if (t + 1 < M_ / 128) stage(cur ^ 1, (t + 1) * 128);

    const unsigned char* Kc = Ks[cur];
    const unsigned char* Vc = Vs[cur];

    f32x4 s[8] = {};
    __builtin_amdgcn_s_setprio(1);
    #pragma unroll
    for (int nf = 0; nf < 8; ++nf) {
      const unsigned char* kr = Kc + (nf * 16 + r) * 128;
      ull2 ka = *(const ull2*)(kr + ((g * 32) ^ fx));
      ull2 kb2 = *(const ull2*)(kr + ((g * 32 + 16) ^ fx));
      s[nf] = MFMA8((long long)ka[0], qf[0], s[nf]);
      s[nf] = MFMA8((long long)ka[1], qf[1], s[nf]);
      s[nf] = MFMA8((long long)kb2[0], qf[2], s[nf]);
      s[nf] = MFMA8((long long)kb2[1], qf[3], s[nf]);
    }
    __builtin_amdgcn_s_setprio(0);

    #pragma unroll
    for (int nf = 0; nf < 8; ++nf) {
      float p0 = exp2a(s[nf][0] * escale), p1 = exp2a(s[nf][1] * escale),
            p2 = exp2a(s[nf][2] * escale), p3 = exp2a(s[nf][3] * escale);
      uint32_t w = 0;
      w = (uint32_t)__builtin_amdgcn_cvt_pk_fp8_f32(p0, p1, (int)w, false);
      w = (uint32_t)__builtin_amdgcn_cvt_pk_fp8_f32(p2, p3, (int)w, true);
      int pbase = ((nf & 1) * 2 + (g >> 1)) * 32 + (nf >> 1) * 8 + (g & 1) * 4;
      *(uint32_t*)(Pw + r * 128 + (pbase ^ fx)) = w;
    }

    ull2 pa01 = *(const ull2*)(Pw + r * 128 + ((g * 32) ^ fx));
    ull2 pa23 = *(const ull2*)(Pw + r * 128 + ((g * 32 + 16) ^ fx));
    __builtin_amdgcn_s_setprio(1);
    ol = MFMA8((long long)pa01[0], ONES, ol);
    ol = MFMA8((long long)pa01[1], ONES, ol);
    ol = MFMA8((long long)pa23[0], ONES, ol);
    ol = MFMA8((long long)pa23[1], ONES, ol);
    #pragma unroll
    for (int nf2 = 0; nf2 < 8; ++nf2) {
      const unsigned char* vr = Vc + (nf2 * 16 + r) * 128;
      ull2 va = *(const ull2*)(vr + ((g * 32) ^ fx));
      ull2 vb2 = *(const ull2*)(vr + ((g * 32 + 16) ^ fx));
      o[nf2] = MFMA8((long long)pa01[0], (long long)va[0], o[nf2]);
      o[nf2] = MFMA8((long long)pa01[1], (long long)va[1], o[nf2]);
      o[nf2] = MFMA8((long long)pa23[0], (long long)vb2[0], o[nf2]);
      o[nf2] = MFMA8((long long)pa23[1], (long long)vb2[1], o[nf2]);
    }
    __builtin_amdgcn_s_setprio(0);
    __syncthreads();
    cur ^= 1;
  }

  float invA[4];
  #pragma unroll
  for (int i = 0; i < 4; ++i) invA[i] = 0.03125f / ol[i];
  unsigned short* rr = ret + ((size_t)(b * S_) + s0 + wave * 16) * E_ + h * D_;
  #pragma unroll
  for (int nf2 = 0; nf2 < 8; ++nf2)
    #pragma unroll
    for (int i = 0; i < 4; ++i)
      rr[(size_t)(g * 4 + i) * E_ + nf2 * 16 + r] = f2bf(o[nf2][i] * invA[i]);
}

// ---------------- final: out = query + rmsnorm(retrieved)*w ----------------
__global__ __launch_bounds__(256) void final_kernel(
    const unsigned short* __restrict__ ret, const float* __restrict__ w,
    const float* __restrict__ query, float* __restrict__ out)
{
  const int row = blockIdx.x;
  const int tid = threadIdx.x;
  u16x8 hv = *(const u16x8*)(ret + (size_t)row * E_ + tid * 8);
  float x[8];
  float ss = 0.f;
  #pragma unroll
  for (int j = 0; j < 8; ++j) { x[j] = bf2f(hv[j]); ss += x[j] * x[j]; }
  float tot = block_sum(ss);
  float sc = rsqrtf(tot * (1.0f / E_) + 1e-5f);
  const float* qr = query + (size_t)row * E_ + tid * 8;
  const float* wr = w + tid * 8;
  float o[8];
  #pragma unroll
  for (int j = 0; j < 8; ++j) o[j] = qr[j] + x[j] * sc * wr[j];
  float4* op = (float4*)(out + (size_t)row * E_ + tid * 8);
  op[0] = make_float4(o[0], o[1], o[2], o[3]);
  op[1] = make_float4(o[4], o[5], o[6], o[7]);
}

extern "C" void kernel_launch(void* const* d_in, const int* in_sizes, int n_in,
                              void* d_out, int out_size, void* d_ws, size_t ws_size,
                              hipStream_t stream) {
  const float* query = (const float*)d_in[0];
  const float* sp    = (const float*)d_in[1];
  const float* wq    = (const float*)d_in[2];
  const float* wk    = (const float*)d_in[3];
  const float* wv    = (const float*)d_in[4];
  const float* beta  = (const float*)d_in[5];
  const float* nqw   = (const float*)d_in[6];
  const float* nrw   = (const float*)d_in[7];
  float* out = (float*)d_out;

  char* ws = (char*)d_ws;
  unsigned char*  wqb = (unsigned char*)(ws + 0);                     // 4 MB (fp8)
  unsigned char*  qn  = (unsigned char*)(ws + ((size_t)8 << 20));     // 8 MB (fp8)
  unsigned char*  qb  = (unsigned char*)(ws + ((size_t)24 << 20));    // 8 MB (fp8)
  unsigned char*  kb  = (unsigned char*)(ws + ((size_t)32 << 20));    // 4 MB (fp8)
  unsigned char*  vtb = (unsigned char*)(ws + ((size_t)36 << 20));    // 4 MB (fp8)
  unsigned short* ret = (unsigned short*)(ws + ((size_t)40 << 20));   // 16 MB (bf16)

  f32_to_fp8_kernel<<<2048, 256, 0, stream>>>(wq, wqb, E_ * E_ / 8);
  rmsnorm_q_kernel<<<B_ * S_, 256, 0, stream>>>(query, nqw, qn);
  gemm_qproj<<<(B_ * S_ / 128) * (E_ / 128), 256, 0, stream>>>(
      qn, wqb, qb, B_ * S_, E_, E_);
  proj_kv_kernel<<<dim3(M_ / 64, H_), 256, 0, stream>>>(sp, wk, wv, kb, vtb);
  attn_kernel<<<dim3(S_ / 128, H_, B_), 512, 0, stream>>>(qb, kb, vtb, beta, ret);
  final_kernel<<<B_ * S_, 256, 0, stream>>>(ret, nrw, query, out);
}

// Round 18
// 133.163 us; speedup vs baseline: 1.0077x; 1.0077x over previous
//
#include <hip/hip_runtime.h>
#include <hip/hip_bf16.h>
#include <stdint.h>

typedef __attribute__((ext_vector_type(8))) short bf16x8;
typedef __attribute__((ext_vector_type(4))) float f32x4;
typedef __attribute__((ext_vector_type(8))) unsigned short u16x8;
typedef __attribute__((ext_vector_type(4))) unsigned short u16x4;
typedef __attribute__((ext_vector_type(2))) unsigned long long ull2;

#define B_ 2
#define S_ 2048
#define E_ 2048
#define H_ 16
#define M_ 2048
#define D_ 128

#define MFMA16(a, b, c) __builtin_amdgcn_mfma_f32_16x16x32_bf16(a, b, c, 0, 0, 0)
#define MFMA8(a, b, c) __builtin_amdgcn_mfma_f32_16x16x32_fp8_fp8(a, b, c, 0, 0, 0)

__device__ inline unsigned short f2bf(float f) {
  union { float f; unsigned u; } v; v.f = f;
  unsigned r = v.u + 0x7FFFu + ((v.u >> 16) & 1u);
  return (unsigned short)(r >> 16);
}
__device__ inline float bf2f(unsigned short h) {
  union { unsigned u; float f; } v; v.u = ((unsigned)h) << 16;
  return v.f;
}

// f32 -> e4m3 single byte via HW converter (branch-free; verified r12-r17)
__device__ inline unsigned char f2e8(float f) {
  return (unsigned char)(__builtin_amdgcn_cvt_pk_fp8_f32(f, f, 0, false) & 0xFF);
}
// 4 floats -> 4 packed e4m3 bytes (verified pattern)
__device__ inline uint32_t pk4e8(float a, float b, float c, float d) {
  uint32_t w = 0;
  w = (uint32_t)__builtin_amdgcn_cvt_pk_fp8_f32(a, b, (int)w, false);
  w = (uint32_t)__builtin_amdgcn_cvt_pk_fp8_f32(c, d, (int)w, true);
  return w;
}

// native 2^x
__device__ inline float exp2a(float x) {
  float r;
  asm("v_exp_f32 %0, %1" : "=v"(r) : "v"(x));
  return r;
}

__device__ inline void gload_lds16(const void* g, void* l) {
  __builtin_amdgcn_global_load_lds(
      (__attribute__((address_space(1))) void*)g,
      (__attribute__((address_space(3))) void*)l, 16, 0, 0);
}

__device__ inline bf16x8 pack8(float4 f0, float4 f1) {
  bf16x8 o;
  o[0] = (short)f2bf(f0.x); o[1] = (short)f2bf(f0.y);
  o[2] = (short)f2bf(f0.z); o[3] = (short)f2bf(f0.w);
  o[4] = (short)f2bf(f1.x); o[5] = (short)f2bf(f1.y);
  o[6] = (short)f2bf(f1.z); o[7] = (short)f2bf(f1.w);
  return o;
}

__device__ inline float block_sum(float v) {
  __shared__ float red[4];
  #pragma unroll
  for (int o = 32; o > 0; o >>= 1) v += __shfl_xor(v, o);
  int tid = threadIdx.x;
  if ((tid & 63) == 0) red[tid >> 6] = v;
  __syncthreads();
  return red[0] + red[1] + red[2] + red[3];
}

// pi(col) within a 128-col group: bits[6:5] <-> [4:3]  (col%8 preserved)
__device__ inline int pi_pos(int c) {
  return (c & ~127) | (((c >> 3) & 3) * 32) | (((c >> 5) & 3) * 8) | (c & 7);
}

// ---------------- fused producers: proj_kv | wq->fp8 | rmsnorm(q)->fp8 ----------------
// All three are mutually independent (read only harness inputs); one launch lets
// them overlap instead of serializing on the stream. Each block takes exactly
// one branch (block-uniform barriers). Bodies verbatim from verified kernels.
#define PREP_PROJ 512
#define PREP_CONV 2048
#define PREP_NORM 4096
__global__ __launch_bounds__(256, 2) void prep_kernel(
    const float* __restrict__ query, const float* __restrict__ sp,
    const float* __restrict__ wq, const float* __restrict__ wk,
    const float* __restrict__ wv, const float* __restrict__ nqw,
    unsigned char* __restrict__ wqb, unsigned char* __restrict__ qn,
    unsigned char* __restrict__ kout, unsigned char* __restrict__ vtout)
{
  const int bid = blockIdx.x;
  const int tid = threadIdx.x;

  if (bid < PREP_PROJ) {
    // ---- proj_kv: fused K/V projections (fp8 out, x32, pi-permuted)
    const int idx = bid;
    const int m0 = (idx & 31) * 64;
    const int h = idx >> 5;
    const int wave = tid >> 6, lane = tid & 63;
    const int r = lane & 15, g = lane >> 4;
    const int wm = (wave >> 1) * 32, wn = (wave & 1) * 64;
    const float* spb = sp + ((size_t)h * M_ + m0) * D_;
    f32x4 acck[2][4] = {};
    f32x4 accv[2][4] = {};
    #pragma unroll
    for (int kc = 0; kc < 4; ++kc) {
      bf16x8 a[2], bk[4], bv[4];
      #pragma unroll
      for (int m = 0; m < 2; ++m) {
        const float* p = spb + (size_t)(wm + m * 16 + r) * D_ + kc * 32 + g * 8;
        a[m] = pack8(*(const float4*)p, *(const float4*)(p + 4));
      }
      #pragma unroll
      for (int n = 0; n < 4; ++n) {
        const float* pk = wk + (size_t)(wn + n * 16 + r) * D_ + kc * 32 + g * 8;
        bk[n] = pack8(*(const float4*)pk, *(const float4*)(pk + 4));
        const float* pv = wv + (size_t)(wn + n * 16 + r) * D_ + kc * 32 + g * 8;
        bv[n] = pack8(*(const float4*)pv, *(const float4*)(pv + 4));
      }
      #pragma unroll
      for (int m = 0; m < 2; ++m)
        #pragma unroll
        for (int n = 0; n < 4; ++n) {
          acck[m][n] = MFMA16(a[m], bk[n], acck[m][n]);
          accv[m][n] = MFMA16(a[m], bv[n], accv[m][n]);
        }
    }
    #pragma unroll
    for (int m = 0; m < 2; ++m)
      #pragma unroll
      for (int n = 0; n < 4; ++n)
        #pragma unroll
        for (int i = 0; i < 4; ++i) {
          int d = wn + n * 16 + r;
          kout[((size_t)h * M_ + m0 + wm + m * 16 + g * 4 + i) * D_ + pi_pos(d)]
              = f2e8(acck[m][n][i] * 32.0f);
          int mc = m0 + wm + m * 16 + g * 4 + i;
          int mp = (mc & ~127) | (pi_pos(mc & 127));
          vtout[((size_t)h * D_ + wn + n * 16 + r) * M_ + mp]
              = f2e8(accv[m][n][i] * 32.0f);
        }
  } else if (bid < PREP_PROJ + PREP_CONV) {
    // ---- wq: f32 -> fp8 pi-permuted
    int i = (bid - PREP_PROJ) * 256 + tid;
    const float* p = wq + (size_t)i * 8;
    float4 a = *(const float4*)p, b = *(const float4*)(p + 4);
    uint2 pk;
    pk.x = pk4e8(a.x, a.y, a.z, a.w);
    pk.y = pk4e8(b.x, b.y, b.z, b.w);
    size_t flat = (size_t)i * 8;
    int c = (int)(flat & (E_ - 1));
    *(uint2*)(wqb + (flat - c) + pi_pos(c)) = pk;
  } else {
    // ---- RMSNorm(query) -> fp8 qn (pi-permuted)
    const int row = bid - (PREP_PROJ + PREP_CONV);
    const float* xr = query + (size_t)row * E_;
    float4 v0 = ((const float4*)xr)[tid * 2];
    float4 v1 = ((const float4*)xr)[tid * 2 + 1];
    float ss = v0.x*v0.x + v0.y*v0.y + v0.z*v0.z + v0.w*v0.w
             + v1.x*v1.x + v1.y*v1.y + v1.z*v1.z + v1.w*v1.w;
    float tot = block_sum(ss);
    float sc = rsqrtf(tot * (1.0f / E_) + 1e-5f);
    float vals[8] = {v0.x, v0.y, v0.z, v0.w, v1.x, v1.y, v1.z, v1.w};
    const float* wr = nqw + tid * 8;
    float f[8];
    #pragma unroll
    for (int j = 0; j < 8; ++j) f[j] = vals[j] * sc * wr[j];
    uint2 pk;
    pk.x = pk4e8(f[0], f[1], f[2], f[3]);
    pk.y = pk4e8(f[4], f[5], f[6], f[7]);
    *(uint2*)(qn + (size_t)row * E_ + pi_pos(tid * 8)) = pk;
  }
}

// ---------------- GEMM C[M,N] = A[M,K] @ B[N,K]^T (fp8 in, fp8 out) ----------------
__global__ __launch_bounds__(256) void gemm_qproj(
    const unsigned char* __restrict__ A, const unsigned char* __restrict__ B,
    unsigned char* __restrict__ C, int M, int N, int K)
{
  __shared__ __align__(16) unsigned char As[128 * 128];  // 16KB
  __shared__ __align__(16) unsigned char Bs[128 * 128];  // 16KB
  const int nwg = gridDim.x;
  const int cpx = nwg >> 3;
  const int swz = (blockIdx.x & 7) * cpx + (blockIdx.x >> 3);
  const int mt = M >> 7;
  const int bm = (swz % mt) * 128;
  const int bn = (swz / mt) * 128;
  const int tid = threadIdx.x;
  const int wave = tid >> 6, lane = tid & 63;
  const int r = lane & 15, g = lane >> 4;
  const int wm = (wave >> 1) * 64, wn = (wave & 1) * 64;
  const int fx = (r & 7) << 4;

  f32x4 acc[4][4] = {};

  for (int k0 = 0; k0 < K; k0 += 128) {
    #pragma unroll
    for (int c = 0; c < 4; ++c) {
      int chunk = wave * 4 + c;
      int off = chunk * 1024 + lane * 16;
      int row = off >> 7;
      int cb = (off & 127) ^ ((row & 7) << 4);
      gload_lds16(A + (size_t)(bm + row) * K + k0 + cb, (char*)As + chunk * 1024);
      gload_lds16(B + (size_t)(bn + row) * K + k0 + cb, (char*)Bs + chunk * 1024);
    }
    __syncthreads();
    #pragma unroll
    for (int half = 0; half < 2; ++half) {
      ull2 af[4], bf[4];
      #pragma unroll
      for (int m = 0; m < 4; ++m)
        af[m] = *(const ull2*)((const char*)As + (wm + m * 16 + r) * 128
                               + ((g * 32 + half * 16) ^ fx));
      #pragma unroll
      for (int n = 0; n < 4; ++n)
        bf[n] = *(const ull2*)((const char*)Bs + (wn + n * 16 + r) * 128
                               + ((g * 32 + half * 16) ^ fx));
      #pragma unroll
      for (int m = 0; m < 4; ++m)
        #pragma unroll
        for (int n = 0; n < 4; ++n) {
          acc[m][n] = MFMA8((long long)af[m][0], (long long)bf[n][0], acc[m][n]);
          acc[m][n] = MFMA8((long long)af[m][1], (long long)bf[n][1], acc[m][n]);
        }
    }
    __syncthreads();
  }
  #pragma unroll
  for (int m = 0; m < 4; ++m)
    #pragma unroll
    for (int n = 0; n < 4; ++n)
      #pragma unroll
      for (int i = 0; i < 4; ++i) {
        int row = bm + wm + m * 16 + g * 4 + i;
        int col = bn + wn + n * 16 + r;
        C[(size_t)row * N + col] = f2e8(acc[m][n][i]);
      }
}

// ---------------- flash attention over memory slots (fp8 K/Q/V/P) ----------------
// [r14/r15/r17 verified: ~62.9us, MfmaUtil ~45, absmax 0.046875 — byte-identical]
__global__ __launch_bounds__(512, 4) void attn_kernel(
    const unsigned char* __restrict__ q,    // [B*S][E] e4m3 (plain cols)
    const unsigned char* __restrict__ kb,   // [H][M][D] e4m3 (x32, pi-permuted d)
    const unsigned char* __restrict__ vtb,  // [H][D][M] e4m3 (x32, pi-permuted m%128)
    const float* __restrict__ beta,
    unsigned short* __restrict__ ret)       // [B*S][E] bf16
{
  __shared__ __align__(16) unsigned char Ks[2][128 * 128];  // 2 x 16KB
  __shared__ __align__(16) unsigned char Vs[2][128 * 128];  // 2 x 16KB
  __shared__ __align__(16) unsigned char Ps[8][16 * 128];   // 16KB
  const int s0 = blockIdx.x * 128;
  const int h = blockIdx.y;
  const int b = blockIdx.z;
  const int tid = threadIdx.x, wave = tid >> 6, lane = tid & 63;
  const int r = lane & 15, g = lane >> 4;
  const int fx = (r & 7) << 4;
  const float escale = beta[h] * (0.08838834764831845f * 1.4426950408889634f / 32.0f);

  long long qf[4];
  {
    const unsigned char* qr0 =
        q + ((size_t)(b * S_) + s0 + wave * 16 + r) * E_ + h * D_;
    #pragma unroll
    for (int kc = 0; kc < 4; ++kc)
      qf[kc] = *(const long long*)(qr0 + kc * 32 + g * 8);
  }

  const unsigned char* Kh = kb + (size_t)h * M_ * D_;
  const unsigned char* Vh = vtb + (size_t)h * D_ * M_;
  unsigned char* Pw = Ps[wave];
  const long long ONES = 0x3838383838383838LL;  // e4m3 1.0 x8

  f32x4 o[8] = {};
  f32x4 ol = {};

  auto stage = [&](int buf, int m0) {
    #pragma unroll
    for (int c = 0; c < 2; ++c) {
      int chunk = wave * 2 + c;
      int off = chunk * 1024 + lane * 16;
      int row = off >> 7;
      int cb = (off & 127) ^ ((row & 7) << 4);
      gload_lds16(Kh + (size_t)(m0 + row) * 128 + cb, (char*)Ks[buf] + chunk * 1024);
      gload_lds16(Vh + (size_t)row * M_ + m0 + cb, (char*)Vs[buf] + chunk * 1024);
    }
  };

  stage(0, 0);
  __syncthreads();

  int cur = 0;
  for (int t = 0; t < M_ / 128; ++t) {
    if (t + 1 < M_ / 128) stage(cur ^ 1, (t + 1) * 128);

    const unsigned char* Kc = Ks[cur];
    const unsigned char* Vc = Vs[cur];

    f32x4 s[8] = {};
    __builtin_amdgcn_s_setprio(1);
    #pragma unroll
    for (int nf = 0; nf < 8; ++nf) {
      const unsigned char* kr = Kc + (nf * 16 + r) * 128;
      ull2 ka = *(const ull2*)(kr + ((g * 32) ^ fx));
      ull2 kb2 = *(const ull2*)(kr + ((g * 32 + 16) ^ fx));
      s[nf] = MFMA8((long long)ka[0], qf[0], s[nf]);
      s[nf] = MFMA8((long long)ka[1], qf[1], s[nf]);
      s[nf] = MFMA8((long long)kb2[0], qf[2], s[nf]);
      s[nf] = MFMA8((long long)kb2[1], qf[3], s[nf]);
    }
    __builtin_amdgcn_s_setprio(0);

    #pragma unroll
    for (int nf = 0; nf < 8; ++nf) {
      float p0 = exp2a(s[nf][0] * escale), p1 = exp2a(s[nf][1] * escale),
            p2 = exp2a(s[nf][2] * escale), p3 = exp2a(s[nf][3] * escale);
      uint32_t w = 0;
      w = (uint32_t)__builtin_amdgcn_cvt_pk_fp8_f32(p0, p1, (int)w, false);
      w = (uint32_t)__builtin_amdgcn_cvt_pk_fp8_f32(p2, p3, (int)w, true);
      int pbase = ((nf & 1) * 2 + (g >> 1)) * 32 + (nf >> 1) * 8 + (g & 1) * 4;
      *(uint32_t*)(Pw + r * 128 + (pbase ^ fx)) = w;
    }

    ull2 pa01 = *(const ull2*)(Pw + r * 128 + ((g * 32) ^ fx));
    ull2 pa23 = *(const ull2*)(Pw + r * 128 + ((g * 32 + 16) ^ fx));
    __builtin_amdgcn_s_setprio(1);
    ol = MFMA8((long long)pa01[0], ONES, ol);
    ol = MFMA8((long long)pa01[1], ONES, ol);
    ol = MFMA8((long long)pa23[0], ONES, ol);
    ol = MFMA8((long long)pa23[1], ONES, ol);
    #pragma unroll
    for (int nf2 = 0; nf2 < 8; ++nf2) {
      const unsigned char* vr = Vc + (nf2 * 16 + r) * 128;
      ull2 va = *(const ull2*)(vr + ((g * 32) ^ fx));
      ull2 vb2 = *(const ull2*)(vr + ((g * 32 + 16) ^ fx));
      o[nf2] = MFMA8((long long)pa01[0], (long long)va[0], o[nf2]);
      o[nf2] = MFMA8((long long)pa01[1], (long long)va[1], o[nf2]);
      o[nf2] = MFMA8((long long)pa23[0], (long long)vb2[0], o[nf2]);
      o[nf2] = MFMA8((long long)pa23[1], (long long)vb2[1], o[nf2]);
    }
    __builtin_amdgcn_s_setprio(0);
    __syncthreads();
    cur ^= 1;
  }

  float invA[4];
  #pragma unroll
  for (int i = 0; i < 4; ++i) invA[i] = 0.03125f / ol[i];
  unsigned short* rr = ret + ((size_t)(b * S_) + s0 + wave * 16) * E_ + h * D_;
  #pragma unroll
  for (int nf2 = 0; nf2 < 8; ++nf2)
    #pragma unroll
    for (int i = 0; i < 4; ++i)
      rr[(size_t)(g * 4 + i) * E_ + nf2 * 16 + r] = f2bf(o[nf2][i] * invA[i]);
}

// ---------------- final: out = query + rmsnorm(retrieved)*w ----------------
__global__ __launch_bounds__(256) void final_kernel(
    const unsigned short* __restrict__ ret, const float* __restrict__ w,
    const float* __restrict__ query, float* __restrict__ out)
{
  const int row = blockIdx.x;
  const int tid = threadIdx.x;
  u16x8 hv = *(const u16x8*)(ret + (size_t)row * E_ + tid * 8);
  float x[8];
  float ss = 0.f;
  #pragma unroll
  for (int j = 0; j < 8; ++j) { x[j] = bf2f(hv[j]); ss += x[j] * x[j]; }
  float tot = block_sum(ss);
  float sc = rsqrtf(tot * (1.0f / E_) + 1e-5f);
  const float* qr = query + (size_t)row * E_ + tid * 8;
  const float* wr = w + tid * 8;
  float o[8];
  #pragma unroll
  for (int j = 0; j < 8; ++j) o[j] = qr[j] + x[j] * sc * wr[j];
  float4* op = (float4*)(out + (size_t)row * E_ + tid * 8);
  op[0] = make_float4(o[0], o[1], o[2], o[3]);
  op[1] = make_float4(o[4], o[5], o[6], o[7]);
}

extern "C" void kernel_launch(void* const* d_in, const int* in_sizes, int n_in,
                              void* d_out, int out_size, void* d_ws, size_t ws_size,
                              hipStream_t stream) {
  const float* query = (const float*)d_in[0];
  const float* sp    = (const float*)d_in[1];
  const float* wq    = (const float*)d_in[2];
  const float* wk    = (const float*)d_in[3];
  const float* wv    = (const float*)d_in[4];
  const float* beta  = (const float*)d_in[5];
  const float* nqw   = (const float*)d_in[6];
  const float* nrw   = (const float*)d_in[7];
  float* out = (float*)d_out;

  char* ws = (char*)d_ws;
  unsigned char*  wqb = (unsigned char*)(ws + 0);                     // 4 MB (fp8)
  unsigned char*  qn  = (unsigned char*)(ws + ((size_t)8 << 20));     // 8 MB (fp8)
  unsigned char*  qb  = (unsigned char*)(ws + ((size_t)24 << 20));    // 8 MB (fp8)
  unsigned char*  kb  = (unsigned char*)(ws + ((size_t)32 << 20));    // 4 MB (fp8)
  unsigned char*  vtb = (unsigned char*)(ws + ((size_t)36 << 20));    // 4 MB (fp8)
  unsigned short* ret = (unsigned short*)(ws + ((size_t)40 << 20));   // 16 MB (bf16)

  prep_kernel<<<PREP_PROJ + PREP_CONV + PREP_NORM, 256, 0, stream>>>(
      query, sp, wq, wk, wv, nqw, wqb, qn, kb, vtb);
  gemm_qproj<<<(B_ * S_ / 128) * (E_ / 128), 256, 0, stream>>>(
      qn, wqb, qb, B_ * S_, E_, E_);
  attn_kernel<<<dim3(S_ / 128, H_, B_), 512, 0, stream>>>(qb, kb, vtb, beta, ret);
  final_kernel<<<B_ * S_, 256, 0, stream>>>(ret, nrw, query, out);
}

// Round 19
// 128.127 us; speedup vs baseline: 1.0473x; 1.0393x over previous
//
#include <hip/hip_runtime.h>
#include <hip/hip_bf16.h>
#include <stdint.h>

typedef __attribute__((ext_vector_type(8))) short bf16x8;
typedef __attribute__((ext_vector_type(4))) float f32x4;
typedef __attribute__((ext_vector_type(8))) unsigned short u16x8;
typedef __attribute__((ext_vector_type(4))) unsigned short u16x4;
typedef __attribute__((ext_vector_type(2))) unsigned long long ull2;
typedef __attribute__((ext_vector_type(8))) int i32x8;

#define B_ 2
#define S_ 2048
#define E_ 2048
#define H_ 16
#define M_ 2048
#define D_ 128

#define MFMA16(a, b, c) __builtin_amdgcn_mfma_f32_16x16x32_bf16(a, b, c, 0, 0, 0)
#define MFMA8(a, b, c) __builtin_amdgcn_mfma_f32_16x16x32_fp8_fp8(a, b, c, 0, 0, 0)
// MX-scaled fp8, K=128, unit scales (e8m0 127 = 2^0): plain fp8 GEMM at 2x rate
#define MFMAS(a, b, c) __builtin_amdgcn_mfma_scale_f32_16x16x128_f8f6f4( \
    a, b, c, 0, 0, 0, 127, 0, 127)

__device__ inline unsigned short f2bf(float f) {
  union { float f; unsigned u; } v; v.f = f;
  unsigned r = v.u + 0x7FFFu + ((v.u >> 16) & 1u);
  return (unsigned short)(r >> 16);
}
__device__ inline float bf2f(unsigned short h) {
  union { unsigned u; float f; } v; v.u = ((unsigned)h) << 16;
  return v.f;
}

// f32 -> e4m3 single byte via HW converter (branch-free; verified r12-r18)
__device__ inline unsigned char f2e8(float f) {
  return (unsigned char)(__builtin_amdgcn_cvt_pk_fp8_f32(f, f, 0, false) & 0xFF);
}
// 4 floats -> 4 packed e4m3 bytes (verified pattern)
__device__ inline uint32_t pk4e8(float a, float b, float c, float d) {
  uint32_t w = 0;
  w = (uint32_t)__builtin_amdgcn_cvt_pk_fp8_f32(a, b, (int)w, false);
  w = (uint32_t)__builtin_amdgcn_cvt_pk_fp8_f32(c, d, (int)w, true);
  return w;
}

// native 2^x
__device__ inline float exp2a(float x) {
  float r;
  asm("v_exp_f32 %0, %1" : "=v"(r) : "v"(x));
  return r;
}

__device__ inline void gload_lds16(const void* g, void* l) {
  __builtin_amdgcn_global_load_lds(
      (__attribute__((address_space(1))) void*)g,
      (__attribute__((address_space(3))) void*)l, 16, 0, 0);
}

__device__ inline bf16x8 pack8(float4 f0, float4 f1) {
  bf16x8 o;
  o[0] = (short)f2bf(f0.x); o[1] = (short)f2bf(f0.y);
  o[2] = (short)f2bf(f0.z); o[3] = (short)f2bf(f0.w);
  o[4] = (short)f2bf(f1.x); o[5] = (short)f2bf(f1.y);
  o[6] = (short)f2bf(f1.z); o[7] = (short)f2bf(f1.w);
  return o;
}

__device__ inline float block_sum(float v) {
  __shared__ float red[4];
  #pragma unroll
  for (int o = 32; o > 0; o >>= 1) v += __shfl_xor(v, o);
  int tid = threadIdx.x;
  if ((tid & 63) == 0) red[tid >> 6] = v;
  __syncthreads();
  return red[0] + red[1] + red[2] + red[3];
}

// pi(col) within a 128-col group: bits[6:5] <-> [4:3]  (col%8 preserved)
__device__ inline int pi_pos(int c) {
  return (c & ~127) | (((c >> 3) & 3) * 32) | (((c >> 5) & 3) * 8) | (c & 7);
}

// ---------------- fused producers: proj_kv | wq->fp8 | rmsnorm(q)->fp8 ----------------
#define PREP_PROJ 512
#define PREP_CONV 2048
#define PREP_NORM 4096
__global__ __launch_bounds__(256, 2) void prep_kernel(
    const float* __restrict__ query, const float* __restrict__ sp,
    const float* __restrict__ wq, const float* __restrict__ wk,
    const float* __restrict__ wv, const float* __restrict__ nqw,
    unsigned char* __restrict__ wqb, unsigned char* __restrict__ qn,
    unsigned char* __restrict__ kout, unsigned char* __restrict__ vtout)
{
  const int bid = blockIdx.x;
  const int tid = threadIdx.x;

  if (bid < PREP_PROJ) {
    // ---- proj_kv: fused K/V projections (fp8 out, x32, pi-permuted)
    const int idx = bid;
    const int m0 = (idx & 31) * 64;
    const int h = idx >> 5;
    const int wave = tid >> 6, lane = tid & 63;
    const int r = lane & 15, g = lane >> 4;
    const int wm = (wave >> 1) * 32, wn = (wave & 1) * 64;
    const float* spb = sp + ((size_t)h * M_ + m0) * D_;
    f32x4 acck[2][4] = {};
    f32x4 accv[2][4] = {};
    #pragma unroll
    for (int kc = 0; kc < 4; ++kc) {
      bf16x8 a[2], bk[4], bv[4];
      #pragma unroll
      for (int m = 0; m < 2; ++m) {
        const float* p = spb + (size_t)(wm + m * 16 + r) * D_ + kc * 32 + g * 8;
        a[m] = pack8(*(const float4*)p, *(const float4*)(p + 4));
      }
      #pragma unroll
      for (int n = 0; n < 4; ++n) {
        const float* pk = wk + (size_t)(wn + n * 16 + r) * D_ + kc * 32 + g * 8;
        bk[n] = pack8(*(const float4*)pk, *(const float4*)(pk + 4));
        const float* pv = wv + (size_t)(wn + n * 16 + r) * D_ + kc * 32 + g * 8;
        bv[n] = pack8(*(const float4*)pv, *(const float4*)(pv + 4));
      }
      #pragma unroll
      for (int m = 0; m < 2; ++m)
        #pragma unroll
        for (int n = 0; n < 4; ++n) {
          acck[m][n] = MFMA16(a[m], bk[n], acck[m][n]);
          accv[m][n] = MFMA16(a[m], bv[n], accv[m][n]);
        }
    }
    #pragma unroll
    for (int m = 0; m < 2; ++m)
      #pragma unroll
      for (int n = 0; n < 4; ++n)
        #pragma unroll
        for (int i = 0; i < 4; ++i) {
          int d = wn + n * 16 + r;
          kout[((size_t)h * M_ + m0 + wm + m * 16 + g * 4 + i) * D_ + pi_pos(d)]
              = f2e8(acck[m][n][i] * 32.0f);
          int mc = m0 + wm + m * 16 + g * 4 + i;
          int mp = (mc & ~127) | (pi_pos(mc & 127));
          vtout[((size_t)h * D_ + wn + n * 16 + r) * M_ + mp]
              = f2e8(accv[m][n][i] * 32.0f);
        }
  } else if (bid < PREP_PROJ + PREP_CONV) {
    // ---- wq: f32 -> fp8 pi-permuted
    int i = (bid - PREP_PROJ) * 256 + tid;
    const float* p = wq + (size_t)i * 8;
    float4 a = *(const float4*)p, b = *(const float4*)(p + 4);
    uint2 pk;
    pk.x = pk4e8(a.x, a.y, a.z, a.w);
    pk.y = pk4e8(b.x, b.y, b.z, b.w);
    size_t flat = (size_t)i * 8;
    int c = (int)(flat & (E_ - 1));
    *(uint2*)(wqb + (flat - c) + pi_pos(c)) = pk;
  } else {
    // ---- RMSNorm(query) -> fp8 qn (pi-permuted)
    const int row = bid - (PREP_PROJ + PREP_CONV);
    const float* xr = query + (size_t)row * E_;
    float4 v0 = ((const float4*)xr)[tid * 2];
    float4 v1 = ((const float4*)xr)[tid * 2 + 1];
    float ss = v0.x*v0.x + v0.y*v0.y + v0.z*v0.z + v0.w*v0.w
             + v1.x*v1.x + v1.y*v1.y + v1.z*v1.z + v1.w*v1.w;
    float tot = block_sum(ss);
    float sc = rsqrtf(tot * (1.0f / E_) + 1e-5f);
    float vals[8] = {v0.x, v0.y, v0.z, v0.w, v1.x, v1.y, v1.z, v1.w};
    const float* wr = nqw + tid * 8;
    float f[8];
    #pragma unroll
    for (int j = 0; j < 8; ++j) f[j] = vals[j] * sc * wr[j];
    uint2 pk;
    pk.x = pk4e8(f[0], f[1], f[2], f[3]);
    pk.y = pk4e8(f[4], f[5], f[6], f[7]);
    *(uint2*)(qn + (size_t)row * E_ + pi_pos(tid * 8)) = pk;
  }
}

// ---------------- GEMM C[M,N] = A[M,K] @ B[N,K]^T (fp8 in, fp8 out, MX-rate) ----------------
// BK=128 = one K=128 MFMA-scale per fragment pair (2x the non-scaled fp8 rate;
// unit e8m0 scales). A/B registers packed from IDENTICAL physical LDS byte
// positions in identical order -> lane->k permutation cancels (r14-verified
// argument); C/D layout shape-determined, epilogue unchanged.
__global__ __launch_bounds__(256) void gemm_qproj(
    const unsigned char* __restrict__ A, const unsigned char* __restrict__ B,
    unsigned char* __restrict__ C, int M, int N, int K)
{
  __shared__ __align__(16) unsigned char As[128 * 128];  // 16KB
  __shared__ __align__(16) unsigned char Bs[128 * 128];  // 16KB
  const int nwg = gridDim.x;
  const int cpx = nwg >> 3;
  const int swz = (blockIdx.x & 7) * cpx + (blockIdx.x >> 3);
  const int mt = M >> 7;
  const int bm = (swz % mt) * 128;
  const int bn = (swz / mt) * 128;
  const int tid = threadIdx.x;
  const int wave = tid >> 6, lane = tid & 63;
  const int r = lane & 15, g = lane >> 4;
  const int wm = (wave >> 1) * 64, wn = (wave & 1) * 64;
  const int fx = (r & 7) << 4;

  f32x4 acc[4][4] = {};

  for (int k0 = 0; k0 < K; k0 += 128) {
    #pragma unroll
    for (int c = 0; c < 4; ++c) {
      int chunk = wave * 4 + c;
      int off = chunk * 1024 + lane * 16;
      int row = off >> 7;
      int cb = (off & 127) ^ ((row & 7) << 4);
      gload_lds16(A + (size_t)(bm + row) * K + k0 + cb, (char*)As + chunk * 1024);
      gload_lds16(B + (size_t)(bn + row) * K + k0 + cb, (char*)Bs + chunk * 1024);
    }
    __syncthreads();
    {
      union U { ull2 u2[2]; i32x8 v; };
      U af[4], bf[4];
      #pragma unroll
      for (int m = 0; m < 4; ++m) {
        const char* pr = (const char*)As + (wm + m * 16 + r) * 128;
        af[m].u2[0] = *(const ull2*)(pr + ((g * 32) ^ fx));
        af[m].u2[1] = *(const ull2*)(pr + ((g * 32 + 16) ^ fx));
      }
      #pragma unroll
      for (int n = 0; n < 4; ++n) {
        const char* pr = (const char*)Bs + (wn + n * 16 + r) * 128;
        bf[n].u2[0] = *(const ull2*)(pr + ((g * 32) ^ fx));
        bf[n].u2[1] = *(const ull2*)(pr + ((g * 32 + 16) ^ fx));
      }
      #pragma unroll
      for (int m = 0; m < 4; ++m)
        #pragma unroll
        for (int n = 0; n < 4; ++n)
          acc[m][n] = MFMAS(af[m].v, bf[n].v, acc[m][n]);
    }
    __syncthreads();
  }
  #pragma unroll
  for (int m = 0; m < 4; ++m)
    #pragma unroll
    for (int n = 0; n < 4; ++n)
      #pragma unroll
      for (int i = 0; i < 4; ++i) {
        int row = bm + wm + m * 16 + g * 4 + i;
        int col = bn + wn + n * 16 + r;
        C[(size_t)row * N + col] = f2e8(acc[m][n][i]);
      }
}

// ---------------- flash attention over memory slots (fp8 K/Q/V/P) ----------------
// [r14/r15/r17/r18 verified: ~62.9us, MfmaUtil ~45, absmax 0.046875 — byte-identical]
__global__ __launch_bounds__(512, 4) void attn_kernel(
    const unsigned char* __restrict__ q,    // [B*S][E] e4m3 (plain cols)
    const unsigned char* __restrict__ kb,   // [H][M][D] e4m3 (x32, pi-permuted d)
    const unsigned char* __restrict__ vtb,  // [H][D][M] e4m3 (x32, pi-permuted m%128)
    const float* __restrict__ beta,
    unsigned short* __restrict__ ret)       // [B*S][E] bf16
{
  __shared__ __align__(16) unsigned char Ks[2][128 * 128];  // 2 x 16KB
  __shared__ __align__(16) unsigned char Vs[2][128 * 128];  // 2 x 16KB
  __shared__ __align__(16) unsigned char Ps[8][16 * 128];   // 16KB
  const int s0 = blockIdx.x * 128;
  const int h = blockIdx.y;
  const int b = blockIdx.z;
  const int tid = threadIdx.x, wave = tid >> 6, lane = tid & 63;
  const int r = lane & 15, g = lane >> 4;
  const int fx = (r & 7) << 4;
  const float escale = beta[h] * (0.08838834764831845f * 1.4426950408889634f / 32.0f);

  long long qf[4];
  {
    const unsigned char* qr0 =
        q + ((size_t)(b * S_) + s0 + wave * 16 + r) * E_ + h * D_;
    #pragma unroll
    for (int kc = 0; kc < 4; ++kc)
      qf[kc] = *(const long long*)(qr0 + kc * 32 + g * 8);
  }

  const unsigned char* Kh = kb + (size_t)h * M_ * D_;
  const unsigned char* Vh = vtb + (size_t)h * D_ * M_;
  unsigned char* Pw = Ps[wave];
  const long long ONES = 0x3838383838383838LL;  // e4m3 1.0 x8

  f32x4 o[8] = {};
  f32x4 ol = {};

  auto stage = [&](int buf, int m0) {
    #pragma unroll
    for (int c = 0; c < 2; ++c) {
      int chunk = wave * 2 + c;
      int off = chunk * 1024 + lane * 16;
      int row = off >> 7;
      int cb = (off & 127) ^ ((row & 7) << 4);
      gload_lds16(Kh + (size_t)(m0 + row) * 128 + cb, (char*)Ks[buf] + chunk * 1024);
      gload_lds16(Vh + (size_t)row * M_ + m0 + cb, (char*)Vs[buf] + chunk * 1024);
    }
  };

  stage(0, 0);
  __syncthreads();

  int cur = 0;
  for (int t = 0; t < M_ / 128; ++t) {
    if (t + 1 < M_ / 128) stage(cur ^ 1, (t + 1) * 128);

    const unsigned char* Kc = Ks[cur];
    const unsigned char* Vc = Vs[cur];

    f32x4 s[8] = {};
    __builtin_amdgcn_s_setprio(1);
    #pragma unroll
    for (int nf = 0; nf < 8; ++nf) {
      const unsigned char* kr = Kc + (nf * 16 + r) * 128;
      ull2 ka = *(const ull2*)(kr + ((g * 32) ^ fx));
      ull2 kb2 = *(const ull2*)(kr + ((g * 32 + 16) ^ fx));
      s[nf] = MFMA8((long long)ka[0], qf[0], s[nf]);
      s[nf] = MFMA8((long long)ka[1], qf[1], s[nf]);
      s[nf] = MFMA8((long long)kb2[0], qf[2], s[nf]);
      s[nf] = MFMA8((long long)kb2[1], qf[3], s[nf]);
    }
    __builtin_amdgcn_s_setprio(0);

    #pragma unroll
    for (int nf = 0; nf < 8; ++nf) {
      float p0 = exp2a(s[nf][0] * escale), p1 = exp2a(s[nf][1] * escale),
            p2 = exp2a(s[nf][2] * escale), p3 = exp2a(s[nf][3] * escale);
      uint32_t w = 0;
      w = (uint32_t)__builtin_amdgcn_cvt_pk_fp8_f32(p0, p1, (int)w, false);
      w = (uint32_t)__builtin_amdgcn_cvt_pk_fp8_f32(p2, p3, (int)w, true);
      int pbase = ((nf & 1) * 2 + (g >> 1)) * 32 + (nf >> 1) * 8 + (g & 1) * 4;
      *(uint32_t*)(Pw + r * 128 + (pbase ^ fx)) = w;
    }

    ull2 pa01 = *(const ull2*)(Pw + r * 128 + ((g * 32) ^ fx));
    ull2 pa23 = *(const ull2*)(Pw + r * 128 + ((g * 32 + 16) ^ fx));
    __builtin_amdgcn_s_setprio(1);
    ol = MFMA8((long long)pa01[0], ONES, ol);
    ol = MFMA8((long long)pa01[1], ONES, ol);
    ol = MFMA8((long long)pa23[0], ONES, ol);
    ol = MFMA8((long long)pa23[1], ONES, ol);
    #pragma unroll
    for (int nf2 = 0; nf2 < 8; ++nf2) {
      const unsigned char* vr = Vc + (nf2 * 16 + r) * 128;
      ull2 va = *(const ull2*)(vr + ((g * 32) ^ fx));
      ull2 vb2 = *(const ull2*)(vr + ((g * 32 + 16) ^ fx));
      o[nf2] = MFMA8((long long)pa01[0], (long long)va[0], o[nf2]);
      o[nf2] = MFMA8((long long)pa01[1], (long long)va[1], o[nf2]);
      o[nf2] = MFMA8((long long)pa23[0], (long long)vb2[0], o[nf2]);
      o[nf2] = MFMA8((long long)pa23[1], (long long)vb2[1], o[nf2]);
    }
    __builtin_amdgcn_s_setprio(0);
    __syncthreads();
    cur ^= 1;
  }

  float invA[4];
  #pragma unroll
  for (int i = 0; i < 4; ++i) invA[i] = 0.03125f / ol[i];
  unsigned short* rr = ret + ((size_t)(b * S_) + s0 + wave * 16) * E_ + h * D_;
  #pragma unroll
  for (int nf2 = 0; nf2 < 8; ++nf2)
    #pragma unroll
    for (int i = 0; i < 4; ++i)
      rr[(size_t)(g * 4 + i) * E_ + nf2 * 16 + r] = f2bf(o[nf2][i] * invA[i]);
}

// ---------------- final: out = query + rmsnorm(retrieved)*w ----------------
__global__ __launch_bounds__(256) void final_kernel(
    const unsigned short* __restrict__ ret, const float* __restrict__ w,
    const float* __restrict__ query, float* __restrict__ out)
{
  const int row = blockIdx.x;
  const int tid = threadIdx.x;
  u16x8 hv = *(const u16x8*)(ret + (size_t)row * E_ + tid * 8);
  float x[8];
  float ss = 0.f;
  #pragma unroll
  for (int j = 0; j < 8; ++j) { x[j] = bf2f(hv[j]); ss += x[j] * x[j]; }
  float tot = block_sum(ss);
  float sc = rsqrtf(tot * (1.0f / E_) + 1e-5f);
  const float* qr = query + (size_t)row * E_ + tid * 8;
  const float* wr = w + tid * 8;
  float o[8];
  #pragma unroll
  for (int j = 0; j < 8; ++j) o[j] = qr[j] + x[j] * sc * wr[j];
  float4* op = (float4*)(out + (size_t)row * E_ + tid * 8);
  op[0] = make_float4(o[0], o[1], o[2], o[3]);
  op[1] = make_float4(o[4], o[5], o[6], o[7]);
}

extern "C" void kernel_launch(void* const* d_in, const int* in_sizes, int n_in,
                              void* d_out, int out_size, void* d_ws, size_t ws_size,
                              hipStream_t stream) {
  const float* query = (const float*)d_in[0];
  const float* sp    = (const float*)d_in[1];
  const float* wq    = (const float*)d_in[2];
  const float* wk    = (const float*)d_in[3];
  const float* wv    = (const float*)d_in[4];
  const float* beta  = (const float*)d_in[5];
  const float* nqw   = (const float*)d_in[6];
  const float* nrw   = (const float*)d_in[7];
  float* out = (float*)d_out;

  char* ws = (char*)d_ws;
  unsigned char*  wqb = (unsigned char*)(ws + 0);                     // 4 MB (fp8)
  unsigned char*  qn  = (unsigned char*)(ws + ((size_t)8 << 20));     // 8 MB (fp8)
  unsigned char*  qb  = (unsigned char*)(ws + ((size_t)24 << 20));    // 8 MB (fp8)
  unsigned char*  kb  = (unsigned char*)(ws + ((size_t)32 << 20));    // 4 MB (fp8)
  unsigned char*  vtb = (unsigned char*)(ws + ((size_t)36 << 20));    // 4 MB (fp8)
  unsigned short* ret = (unsigned short*)(ws + ((size_t)40 << 20));   // 16 MB (bf16)

  prep_kernel<<<PREP_PROJ + PREP_CONV + PREP_NORM, 256, 0, stream>>>(
      query, sp, wq, wk, wv, nqw, wqb, qn, kb, vtb);
  gemm_qproj<<<(B_ * S_ / 128) * (E_ / 128), 256, 0, stream>>>(
      qn, wqb, qb, B_ * S_, E_, E_);
  attn_kernel<<<dim3(S_ / 128, H_, B_), 512, 0, stream>>>(qb, kb, vtb, beta, ret);
  final_kernel<<<B_ * S_, 256, 0, stream>>>(ret, nrw, query, out);
}

// Round 20
// 122.878 us; speedup vs baseline: 1.0920x; 1.0427x over previous
//
#include <hip/hip_runtime.h>
#include <hip/hip_bf16.h>
#include <stdint.h>

typedef __attribute__((ext_vector_type(8))) short bf16x8;
typedef __attribute__((ext_vector_type(4))) float f32x4;
typedef __attribute__((ext_vector_type(8))) unsigned short u16x8;
typedef __attribute__((ext_vector_type(4))) unsigned short u16x4;
typedef __attribute__((ext_vector_type(2))) unsigned long long ull2;
typedef __attribute__((ext_vector_type(8))) int i32x8;

#define B_ 2
#define S_ 2048
#define E_ 2048
#define H_ 16
#define M_ 2048
#define D_ 128

#define MFMA16(a, b, c) __builtin_amdgcn_mfma_f32_16x16x32_bf16(a, b, c, 0, 0, 0)
#define MFMA8(a, b, c) __builtin_amdgcn_mfma_f32_16x16x32_fp8_fp8(a, b, c, 0, 0, 0)
// MX-scaled fp8, K=128, unit scales (e8m0 127 = 2^0): plain fp8 math at 2x rate
#define MFMAS(a, b, c) __builtin_amdgcn_mfma_scale_f32_16x16x128_f8f6f4( \
    a, b, c, 0, 0, 0, 127, 0, 127)

union U32x8 { ull2 u2[2]; long long q[4]; i32x8 v; };

__device__ inline unsigned short f2bf(float f) {
  union { float f; unsigned u; } v; v.f = f;
  unsigned r = v.u + 0x7FFFu + ((v.u >> 16) & 1u);
  return (unsigned short)(r >> 16);
}
__device__ inline float bf2f(unsigned short h) {
  union { unsigned u; float f; } v; v.u = ((unsigned)h) << 16;
  return v.f;
}

// f32 -> e4m3 single byte via HW converter (branch-free; verified r12-r19)
__device__ inline unsigned char f2e8(float f) {
  return (unsigned char)(__builtin_amdgcn_cvt_pk_fp8_f32(f, f, 0, false) & 0xFF);
}
// 4 floats -> 4 packed e4m3 bytes (verified pattern)
__device__ inline uint32_t pk4e8(float a, float b, float c, float d) {
  uint32_t w = 0;
  w = (uint32_t)__builtin_amdgcn_cvt_pk_fp8_f32(a, b, (int)w, false);
  w = (uint32_t)__builtin_amdgcn_cvt_pk_fp8_f32(c, d, (int)w, true);
  return w;
}

// native 2^x
__device__ inline float exp2a(float x) {
  float r;
  asm("v_exp_f32 %0, %1" : "=v"(r) : "v"(x));
  return r;
}

__device__ inline void gload_lds16(const void* g, void* l) {
  __builtin_amdgcn_global_load_lds(
      (__attribute__((address_space(1))) void*)g,
      (__attribute__((address_space(3))) void*)l, 16, 0, 0);
}

__device__ inline bf16x8 pack8(float4 f0, float4 f1) {
  bf16x8 o;
  o[0] = (short)f2bf(f0.x); o[1] = (short)f2bf(f0.y);
  o[2] = (short)f2bf(f0.z); o[3] = (short)f2bf(f0.w);
  o[4] = (short)f2bf(f1.x); o[5] = (short)f2bf(f1.y);
  o[6] = (short)f2bf(f1.z); o[7] = (short)f2bf(f1.w);
  return o;
}

__device__ inline float block_sum(float v) {
  __shared__ float red[4];
  #pragma unroll
  for (int o = 32; o > 0; o >>= 1) v += __shfl_xor(v, o);
  int tid = threadIdx.x;
  if ((tid & 63) == 0) red[tid >> 6] = v;
  __syncthreads();
  return red[0] + red[1] + red[2] + red[3];
}

// pi(col) within a 128-col group: bits[6:5] <-> [4:3]  (col%8 preserved)
__device__ inline int pi_pos(int c) {
  return (c & ~127) | (((c >> 3) & 3) * 32) | (((c >> 5) & 3) * 8) | (c & 7);
}

// ---------------- fused producers: proj_kv | wq->fp8 | rmsnorm(q)->fp8 ----------------
#define PREP_PROJ 512
#define PREP_CONV 2048
#define PREP_NORM 4096
__global__ __launch_bounds__(256, 2) void prep_kernel(
    const float* __restrict__ query, const float* __restrict__ sp,
    const float* __restrict__ wq, const float* __restrict__ wk,
    const float* __restrict__ wv, const float* __restrict__ nqw,
    unsigned char* __restrict__ wqb, unsigned char* __restrict__ qn,
    unsigned char* __restrict__ kout, unsigned char* __restrict__ vtout)
{
  const int bid = blockIdx.x;
  const int tid = threadIdx.x;

  if (bid < PREP_PROJ) {
    // ---- proj_kv: fused K/V projections (fp8 out, x32, pi-permuted)
    const int idx = bid;
    const int m0 = (idx & 31) * 64;
    const int h = idx >> 5;
    const int wave = tid >> 6, lane = tid & 63;
    const int r = lane & 15, g = lane >> 4;
    const int wm = (wave >> 1) * 32, wn = (wave & 1) * 64;
    const float* spb = sp + ((size_t)h * M_ + m0) * D_;
    f32x4 acck[2][4] = {};
    f32x4 accv[2][4] = {};
    #pragma unroll
    for (int kc = 0; kc < 4; ++kc) {
      bf16x8 a[2], bk[4], bv[4];
      #pragma unroll
      for (int m = 0; m < 2; ++m) {
        const float* p = spb + (size_t)(wm + m * 16 + r) * D_ + kc * 32 + g * 8;
        a[m] = pack8(*(const float4*)p, *(const float4*)(p + 4));
      }
      #pragma unroll
      for (int n = 0; n < 4; ++n) {
        const float* pk = wk + (size_t)(wn + n * 16 + r) * D_ + kc * 32 + g * 8;
        bk[n] = pack8(*(const float4*)pk, *(const float4*)(pk + 4));
        const float* pv = wv + (size_t)(wn + n * 16 + r) * D_ + kc * 32 + g * 8;
        bv[n] = pack8(*(const float4*)pv, *(const float4*)(pv + 4));
      }
      #pragma unroll
      for (int m = 0; m < 2; ++m)
        #pragma unroll
        for (int n = 0; n < 4; ++n) {
          acck[m][n] = MFMA16(a[m], bk[n], acck[m][n]);
          accv[m][n] = MFMA16(a[m], bv[n], accv[m][n]);
        }
    }
    #pragma unroll
    for (int m = 0; m < 2; ++m)
      #pragma unroll
      for (int n = 0; n < 4; ++n)
        #pragma unroll
        for (int i = 0; i < 4; ++i) {
          int d = wn + n * 16 + r;
          kout[((size_t)h * M_ + m0 + wm + m * 16 + g * 4 + i) * D_ + pi_pos(d)]
              = f2e8(acck[m][n][i] * 32.0f);
          int mc = m0 + wm + m * 16 + g * 4 + i;
          int mp = (mc & ~127) | (pi_pos(mc & 127));
          vtout[((size_t)h * D_ + wn + n * 16 + r) * M_ + mp]
              = f2e8(accv[m][n][i] * 32.0f);
        }
  } else if (bid < PREP_PROJ + PREP_CONV) {
    // ---- wq: f32 -> fp8 pi-permuted
    int i = (bid - PREP_PROJ) * 256 + tid;
    const float* p = wq + (size_t)i * 8;
    float4 a = *(const float4*)p, b = *(const float4*)(p + 4);
    uint2 pk;
    pk.x = pk4e8(a.x, a.y, a.z, a.w);
    pk.y = pk4e8(b.x, b.y, b.z, b.w);
    size_t flat = (size_t)i * 8;
    int c = (int)(flat & (E_ - 1));
    *(uint2*)(wqb + (flat - c) + pi_pos(c)) = pk;
  } else {
    // ---- RMSNorm(query) -> fp8 qn (pi-permuted)
    const int row = bid - (PREP_PROJ + PREP_CONV);
    const float* xr = query + (size_t)row * E_;
    float4 v0 = ((const float4*)xr)[tid * 2];
    float4 v1 = ((const float4*)xr)[tid * 2 + 1];
    float ss = v0.x*v0.x + v0.y*v0.y + v0.z*v0.z + v0.w*v0.w
             + v1.x*v1.x + v1.y*v1.y + v1.z*v1.z + v1.w*v1.w;
    float tot = block_sum(ss);
    float sc = rsqrtf(tot * (1.0f / E_) + 1e-5f);
    float vals[8] = {v0.x, v0.y, v0.z, v0.w, v1.x, v1.y, v1.z, v1.w};
    const float* wr = nqw + tid * 8;
    float f[8];
    #pragma unroll
    for (int j = 0; j < 8; ++j) f[j] = vals[j] * sc * wr[j];
    uint2 pk;
    pk.x = pk4e8(f[0], f[1], f[2], f[3]);
    pk.y = pk4e8(f[4], f[5], f[6], f[7]);
    *(uint2*)(qn + (size_t)row * E_ + pi_pos(tid * 8)) = pk;
  }
}

// ---------------- GEMM C[M,N] = A[M,K] @ B[N,K]^T (fp8 in/out, MX-rate) ----------------
// [r19 verified: MX K=128 unit-scale, absmax unchanged]
__global__ __launch_bounds__(256) void gemm_qproj(
    const unsigned char* __restrict__ A, const unsigned char* __restrict__ B,
    unsigned char* __restrict__ C, int M, int N, int K)
{
  __shared__ __align__(16) unsigned char As[128 * 128];  // 16KB
  __shared__ __align__(16) unsigned char Bs[128 * 128];  // 16KB
  const int nwg = gridDim.x;
  const int cpx = nwg >> 3;
  const int swz = (blockIdx.x & 7) * cpx + (blockIdx.x >> 3);
  const int mt = M >> 7;
  const int bm = (swz % mt) * 128;
  const int bn = (swz / mt) * 128;
  const int tid = threadIdx.x;
  const int wave = tid >> 6, lane = tid & 63;
  const int r = lane & 15, g = lane >> 4;
  const int wm = (wave >> 1) * 64, wn = (wave & 1) * 64;
  const int fx = (r & 7) << 4;

  f32x4 acc[4][4] = {};

  for (int k0 = 0; k0 < K; k0 += 128) {
    #pragma unroll
    for (int c = 0; c < 4; ++c) {
      int chunk = wave * 4 + c;
      int off = chunk * 1024 + lane * 16;
      int row = off >> 7;
      int cb = (off & 127) ^ ((row & 7) << 4);
      gload_lds16(A + (size_t)(bm + row) * K + k0 + cb, (char*)As + chunk * 1024);
      gload_lds16(B + (size_t)(bn + row) * K + k0 + cb, (char*)Bs + chunk * 1024);
    }
    __syncthreads();
    {
      U32x8 af[4], bf[4];
      #pragma unroll
      for (int m = 0; m < 4; ++m) {
        const char* pr = (const char*)As + (wm + m * 16 + r) * 128;
        af[m].u2[0] = *(const ull2*)(pr + ((g * 32) ^ fx));
        af[m].u2[1] = *(const ull2*)(pr + ((g * 32 + 16) ^ fx));
      }
      #pragma unroll
      for (int n = 0; n < 4; ++n) {
        const char* pr = (const char*)Bs + (wn + n * 16 + r) * 128;
        bf[n].u2[0] = *(const ull2*)(pr + ((g * 32) ^ fx));
        bf[n].u2[1] = *(const ull2*)(pr + ((g * 32 + 16) ^ fx));
      }
      #pragma unroll
      for (int m = 0; m < 4; ++m)
        #pragma unroll
        for (int n = 0; n < 4; ++n)
          acc[m][n] = MFMAS(af[m].v, bf[n].v, acc[m][n]);
    }
    __syncthreads();
  }
  #pragma unroll
  for (int m = 0; m < 4; ++m)
    #pragma unroll
    for (int n = 0; n < 4; ++n)
      #pragma unroll
      for (int i = 0; i < 4; ++i) {
        int row = bm + wm + m * 16 + g * 4 + i;
        int col = bn + wn + n * 16 + r;
        C[(size_t)row * N + col] = f2e8(acc[m][n][i]);
      }
}

// ---------------- flash attention over memory slots (fp8, MX-rate MFMA) ----------------
// Same LDS layout/staging/softmax as r17/r18 (verified, absmax 0.046875); the
// four chained K=32 MFMA8 per fragment-pair are fused into one K=128 MFMAS
// (unit scales): 68 -> 17 matrix ops per wave-iter, MFMA pipe cycles halve.
// Operand safety: A/B packed from identical physical byte positions in
// identical order (r19-HW-verified cancellation); C/D layout shape-determined.
__global__ __launch_bounds__(512, 4) void attn_kernel(
    const unsigned char* __restrict__ q,    // [B*S][E] e4m3 (plain cols)
    const unsigned char* __restrict__ kb,   // [H][M][D] e4m3 (x32, pi-permuted d)
    const unsigned char* __restrict__ vtb,  // [H][D][M] e4m3 (x32, pi-permuted m%128)
    const float* __restrict__ beta,
    unsigned short* __restrict__ ret)       // [B*S][E] bf16
{
  __shared__ __align__(16) unsigned char Ks[2][128 * 128];  // 2 x 16KB
  __shared__ __align__(16) unsigned char Vs[2][128 * 128];  // 2 x 16KB
  __shared__ __align__(16) unsigned char Ps[8][16 * 128];   // 16KB
  const int s0 = blockIdx.x * 128;
  const int h = blockIdx.y;
  const int b = blockIdx.z;
  const int tid = threadIdx.x, wave = tid >> 6, lane = tid & 63;
  const int r = lane & 15, g = lane >> 4;
  const int fx = (r & 7) << 4;
  const float escale = beta[h] * (0.08838834764831845f * 1.4426950408889634f / 32.0f);

  // Q fragment packed once: qv byte i holds the same logical d as K physical
  // byte i of the lane's 32B row slice (r14-verified pairing).
  U32x8 qv;
  {
    const unsigned char* qr0 =
        q + ((size_t)(b * S_) + s0 + wave * 16 + r) * E_ + h * D_;
    #pragma unroll
    for (int kc = 0; kc < 4; ++kc)
      qv.q[kc] = *(const long long*)(qr0 + kc * 32 + g * 8);
  }

  const unsigned char* Kh = kb + (size_t)h * M_ * D_;
  const unsigned char* Vh = vtb + (size_t)h * D_ * M_;
  unsigned char* Pw = Ps[wave];
  U32x8 ones8;
  #pragma unroll
  for (int i = 0; i < 4; ++i) ones8.q[i] = 0x3838383838383838LL;  // e4m3 1.0

  f32x4 o[8] = {};
  f32x4 ol = {};

  auto stage = [&](int buf, int m0) {
    #pragma unroll
    for (int c = 0; c < 2; ++c) {
      int chunk = wave * 2 + c;
      int off = chunk * 1024 + lane * 16;
      int row = off >> 7;
      int cb = (off & 127) ^ ((row & 7) << 4);
      gload_lds16(Kh + (size_t)(m0 + row) * 128 + cb, (char*)Ks[buf] + chunk * 1024);
      gload_lds16(Vh + (size_t)row * M_ + m0 + cb, (char*)Vs[buf] + chunk * 1024);
    }
  };

  stage(0, 0);
  __syncthreads();

  int cur = 0;
  for (int t = 0; t < M_ / 128; ++t) {
    if (t + 1 < M_ / 128) stage(cur ^ 1, (t + 1) * 128);

    const unsigned char* Kc = Ks[cur];
    const unsigned char* Vc = Vs[cur];

    // ---- S^T = K @ Q^T : one K=128 MFMAS per nf
    f32x4 s[8] = {};
    __builtin_amdgcn_s_setprio(1);
    #pragma unroll
    for (int nf = 0; nf < 8; ++nf) {
      const unsigned char* kr = Kc + (nf * 16 + r) * 128;
      U32x8 kf;
      kf.u2[0] = *(const ull2*)(kr + ((g * 32) ^ fx));
      kf.u2[1] = *(const ull2*)(kr + ((g * 32 + 16) ^ fx));
      s[nf] = MFMAS(kf.v, qv.v, s[nf]);
    }
    __builtin_amdgcn_s_setprio(0);

    // ---- P = 2^(s*escale), packed e4m3; b32 write at pi(slot) position
    #pragma unroll
    for (int nf = 0; nf < 8; ++nf) {
      float p0 = exp2a(s[nf][0] * escale), p1 = exp2a(s[nf][1] * escale),
            p2 = exp2a(s[nf][2] * escale), p3 = exp2a(s[nf][3] * escale);
      uint32_t w = 0;
      w = (uint32_t)__builtin_amdgcn_cvt_pk_fp8_f32(p0, p1, (int)w, false);
      w = (uint32_t)__builtin_amdgcn_cvt_pk_fp8_f32(p2, p3, (int)w, true);
      int pbase = ((nf & 1) * 2 + (g >> 1)) * 32 + (nf >> 1) * 8 + (g & 1) * 4;
      *(uint32_t*)(Pw + r * 128 + (pbase ^ fx)) = w;
    }

    // ---- O += P @ V ; l += P @ ones : one MFMAS per nf2 (+1 for l)
    U32x8 pv;
    pv.u2[0] = *(const ull2*)(Pw + r * 128 + ((g * 32) ^ fx));
    pv.u2[1] = *(const ull2*)(Pw + r * 128 + ((g * 32 + 16) ^ fx));
    __builtin_amdgcn_s_setprio(1);
    ol = MFMAS(pv.v, ones8.v, ol);
    #pragma unroll
    for (int nf2 = 0; nf2 < 8; ++nf2) {
      const unsigned char* vr = Vc + (nf2 * 16 + r) * 128;
      U32x8 vf;
      vf.u2[0] = *(const ull2*)(vr + ((g * 32) ^ fx));
      vf.u2[1] = *(const ull2*)(vr + ((g * 32 + 16) ^ fx));
      o[nf2] = MFMAS(pv.v, vf.v, o[nf2]);
    }
    __builtin_amdgcn_s_setprio(0);
    __syncthreads();
    cur ^= 1;
  }

  float invA[4];
  #pragma unroll
  for (int i = 0; i < 4; ++i) invA[i] = 0.03125f / ol[i];
  unsigned short* rr = ret + ((size_t)(b * S_) + s0 + wave * 16) * E_ + h * D_;
  #pragma unroll
  for (int nf2 = 0; nf2 < 8; ++nf2)
    #pragma unroll
    for (int i = 0; i < 4; ++i)
      rr[(size_t)(g * 4 + i) * E_ + nf2 * 16 + r] = f2bf(o[nf2][i] * invA[i]);
}

// ---------------- final: out = query + rmsnorm(retrieved)*w ----------------
__global__ __launch_bounds__(256) void final_kernel(
    const unsigned short* __restrict__ ret, const float* __restrict__ w,
    const float* __restrict__ query, float* __restrict__ out)
{
  const int row = blockIdx.x;
  const int tid = threadIdx.x;
  u16x8 hv = *(const u16x8*)(ret + (size_t)row * E_ + tid * 8);
  float x[8];
  float ss = 0.f;
  #pragma unroll
  for (int j = 0; j < 8; ++j) { x[j] = bf2f(hv[j]); ss += x[j] * x[j]; }
  float tot = block_sum(ss);
  float sc = rsqrtf(tot * (1.0f / E_) + 1e-5f);
  const float* qr = query + (size_t)row * E_ + tid * 8;
  const float* wr = w + tid * 8;
  float o[8];
  #pragma unroll
  for (int j = 0; j < 8; ++j) o[j] = qr[j] + x[j] * sc * wr[j];
  float4* op = (float4*)(out + (size_t)row * E_ + tid * 8);
  op[0] = make_float4(o[0], o[1], o[2], o[3]);
  op[1] = make_float4(o[4], o[5], o[6], o[7]);
}

extern "C" void kernel_launch(void* const* d_in, const int* in_sizes, int n_in,
                              void* d_out, int out_size, void* d_ws, size_t ws_size,
                              hipStream_t stream) {
  const float* query = (const float*)d_in[0];
  const float* sp    = (const float*)d_in[1];
  const float* wq    = (const float*)d_in[2];
  const float* wk    = (const float*)d_in[3];
  const float* wv    = (const float*)d_in[4];
  const float* beta  = (const float*)d_in[5];
  const float* nqw   = (const float*)d_in[6];
  const float* nrw   = (const float*)d_in[7];
  float* out = (float*)d_out;

  char* ws = (char*)d_ws;
  unsigned char*  wqb = (unsigned char*)(ws + 0);                     // 4 MB (fp8)
  unsigned char*  qn  = (unsigned char*)(ws + ((size_t)8 << 20));     // 8 MB (fp8)
  unsigned char*  qb  = (unsigned char*)(ws + ((size_t)24 << 20));    // 8 MB (fp8)
  unsigned char*  kb  = (unsigned char*)(ws + ((size_t)32 << 20));    // 4 MB (fp8)
  unsigned char*  vtb = (unsigned char*)(ws + ((size_t)36 << 20));    // 4 MB (fp8)
  unsigned short* ret = (unsigned short*)(ws + ((size_t)40 << 20));   // 16 MB (bf16)

  prep_kernel<<<PREP_PROJ + PREP_CONV + PREP_NORM, 256, 0, stream>>>(
      query, sp, wq, wk, wv, nqw, wqb, qn, kb, vtb);
  gemm_qproj<<<(B_ * S_ / 128) * (E_ / 128), 256, 0, stream>>>(
      qn, wqb, qb, B_ * S_, E_, E_);
  attn_kernel<<<dim3(S_ / 128, H_, B_), 512, 0, stream>>>(qb, kb, vtb, beta, ret);
  final_kernel<<<B_ * S_, 256, 0, stream>>>(ret, nrw, query, out);
}

// Round 21
// 120.111 us; speedup vs baseline: 1.1171x; 1.0230x over previous
//
#include <hip/hip_runtime.h>
#include <hip/hip_bf16.h>
#include <stdint.h>

typedef __attribute__((ext_vector_type(8))) short bf16x8;
typedef __attribute__((ext_vector_type(4))) float f32x4;
typedef __attribute__((ext_vector_type(8))) unsigned short u16x8;
typedef __attribute__((ext_vector_type(4))) unsigned short u16x4;
typedef __attribute__((ext_vector_type(2))) unsigned long long ull2;
typedef __attribute__((ext_vector_type(8))) int i32x8;

#define B_ 2
#define S_ 2048
#define E_ 2048
#define H_ 16
#define M_ 2048
#define D_ 128

#define MFMA16(a, b, c) __builtin_amdgcn_mfma_f32_16x16x32_bf16(a, b, c, 0, 0, 0)
#define MFMA8(a, b, c) __builtin_amdgcn_mfma_f32_16x16x32_fp8_fp8(a, b, c, 0, 0, 0)
// MX-scaled fp8, K=128, unit scales (e8m0 127 = 2^0): plain fp8 math at 2x rate
#define MFMAS(a, b, c) __builtin_amdgcn_mfma_scale_f32_16x16x128_f8f6f4( \
    a, b, c, 0, 0, 0, 127, 0, 127)

union U32x8 { ull2 u2[2]; long long q[4]; i32x8 v; };

__device__ inline unsigned short f2bf(float f) {
  union { float f; unsigned u; } v; v.f = f;
  unsigned r = v.u + 0x7FFFu + ((v.u >> 16) & 1u);
  return (unsigned short)(r >> 16);
}
__device__ inline float bf2f(unsigned short h) {
  union { unsigned u; float f; } v; v.u = ((unsigned)h) << 16;
  return v.f;
}

// f32 -> e4m3 single byte via HW converter (branch-free; verified r12-r20)
__device__ inline unsigned char f2e8(float f) {
  return (unsigned char)(__builtin_amdgcn_cvt_pk_fp8_f32(f, f, 0, false) & 0xFF);
}
// 4 floats -> 4 packed e4m3 bytes (verified pattern)
__device__ inline uint32_t pk4e8(float a, float b, float c, float d) {
  uint32_t w = 0;
  w = (uint32_t)__builtin_amdgcn_cvt_pk_fp8_f32(a, b, (int)w, false);
  w = (uint32_t)__builtin_amdgcn_cvt_pk_fp8_f32(c, d, (int)w, true);
  return w;
}

// native 2^x
__device__ inline float exp2a(float x) {
  float r;
  asm("v_exp_f32 %0, %1" : "=v"(r) : "v"(x));
  return r;
}

__device__ inline void gload_lds16(const void* g, void* l) {
  __builtin_amdgcn_global_load_lds(
      (__attribute__((address_space(1))) void*)g,
      (__attribute__((address_space(3))) void*)l, 16, 0, 0);
}

__device__ inline bf16x8 pack8(float4 f0, float4 f1) {
  bf16x8 o;
  o[0] = (short)f2bf(f0.x); o[1] = (short)f2bf(f0.y);
  o[2] = (short)f2bf(f0.z); o[3] = (short)f2bf(f0.w);
  o[4] = (short)f2bf(f1.x); o[5] = (short)f2bf(f1.y);
  o[6] = (short)f2bf(f1.z); o[7] = (short)f2bf(f1.w);
  return o;
}

__device__ inline float block_sum(float v) {
  __shared__ float red[4];
  #pragma unroll
  for (int o = 32; o > 0; o >>= 1) v += __shfl_xor(v, o);
  int tid = threadIdx.x;
  if ((tid & 63) == 0) red[tid >> 6] = v;
  __syncthreads();
  return red[0] + red[1] + red[2] + red[3];
}

// pi(col) within a 128-col group: bits[6:5] <-> [4:3]  (col%8 preserved)
__device__ inline int pi_pos(int c) {
  return (c & ~127) | (((c >> 3) & 3) * 32) | (((c >> 5) & 3) * 8) | (c & 7);
}

// ---------------- fused producers: proj_kv | wq->fp8 | rmsnorm(q)->fp8 ----------------
#define PREP_PROJ 512
#define PREP_CONV 2048
#define PREP_NORM 4096
__global__ __launch_bounds__(256, 2) void prep_kernel(
    const float* __restrict__ query, const float* __restrict__ sp,
    const float* __restrict__ wq, const float* __restrict__ wk,
    const float* __restrict__ wv, const float* __restrict__ nqw,
    unsigned char* __restrict__ wqb, unsigned char* __restrict__ qn,
    unsigned char* __restrict__ kout, unsigned char* __restrict__ vtout)
{
  const int bid = blockIdx.x;
  const int tid = threadIdx.x;

  if (bid < PREP_PROJ) {
    // ---- proj_kv: fused K/V projections (fp8 out, x32, pi-permuted)
    const int idx = bid;
    const int m0 = (idx & 31) * 64;
    const int h = idx >> 5;
    const int wave = tid >> 6, lane = tid & 63;
    const int r = lane & 15, g = lane >> 4;
    const int wm = (wave >> 1) * 32, wn = (wave & 1) * 64;
    const float* spb = sp + ((size_t)h * M_ + m0) * D_;
    f32x4 acck[2][4] = {};
    f32x4 accv[2][4] = {};
    #pragma unroll
    for (int kc = 0; kc < 4; ++kc) {
      bf16x8 a[2], bk[4], bv[4];
      #pragma unroll
      for (int m = 0; m < 2; ++m) {
        const float* p = spb + (size_t)(wm + m * 16 + r) * D_ + kc * 32 + g * 8;
        a[m] = pack8(*(const float4*)p, *(const float4*)(p + 4));
      }
      #pragma unroll
      for (int n = 0; n < 4; ++n) {
        const float* pk = wk + (size_t)(wn + n * 16 + r) * D_ + kc * 32 + g * 8;
        bk[n] = pack8(*(const float4*)pk, *(const float4*)(pk + 4));
        const float* pv = wv + (size_t)(wn + n * 16 + r) * D_ + kc * 32 + g * 8;
        bv[n] = pack8(*(const float4*)pv, *(const float4*)(pv + 4));
      }
      #pragma unroll
      for (int m = 0; m < 2; ++m)
        #pragma unroll
        for (int n = 0; n < 4; ++n) {
          acck[m][n] = MFMA16(a[m], bk[n], acck[m][n]);
          accv[m][n] = MFMA16(a[m], bv[n], accv[m][n]);
        }
    }
    #pragma unroll
    for (int m = 0; m < 2; ++m)
      #pragma unroll
      for (int n = 0; n < 4; ++n)
        #pragma unroll
        for (int i = 0; i < 4; ++i) {
          int d = wn + n * 16 + r;
          kout[((size_t)h * M_ + m0 + wm + m * 16 + g * 4 + i) * D_ + pi_pos(d)]
              = f2e8(acck[m][n][i] * 32.0f);
          int mc = m0 + wm + m * 16 + g * 4 + i;
          int mp = (mc & ~127) | (pi_pos(mc & 127));
          vtout[((size_t)h * D_ + wn + n * 16 + r) * M_ + mp]
              = f2e8(accv[m][n][i] * 32.0f);
        }
  } else if (bid < PREP_PROJ + PREP_CONV) {
    // ---- wq: f32 -> fp8 pi-permuted
    int i = (bid - PREP_PROJ) * 256 + tid;
    const float* p = wq + (size_t)i * 8;
    float4 a = *(const float4*)p, b = *(const float4*)(p + 4);
    uint2 pk;
    pk.x = pk4e8(a.x, a.y, a.z, a.w);
    pk.y = pk4e8(b.x, b.y, b.z, b.w);
    size_t flat = (size_t)i * 8;
    int c = (int)(flat & (E_ - 1));
    *(uint2*)(wqb + (flat - c) + pi_pos(c)) = pk;
  } else {
    // ---- RMSNorm(query) -> fp8 qn (pi-permuted)
    const int row = bid - (PREP_PROJ + PREP_CONV);
    const float* xr = query + (size_t)row * E_;
    float4 v0 = ((const float4*)xr)[tid * 2];
    float4 v1 = ((const float4*)xr)[tid * 2 + 1];
    float ss = v0.x*v0.x + v0.y*v0.y + v0.z*v0.z + v0.w*v0.w
             + v1.x*v1.x + v1.y*v1.y + v1.z*v1.z + v1.w*v1.w;
    float tot = block_sum(ss);
    float sc = rsqrtf(tot * (1.0f / E_) + 1e-5f);
    float vals[8] = {v0.x, v0.y, v0.z, v0.w, v1.x, v1.y, v1.z, v1.w};
    const float* wr = nqw + tid * 8;
    float f[8];
    #pragma unroll
    for (int j = 0; j < 8; ++j) f[j] = vals[j] * sc * wr[j];
    uint2 pk;
    pk.x = pk4e8(f[0], f[1], f[2], f[3]);
    pk.y = pk4e8(f[4], f[5], f[6], f[7]);
    *(uint2*)(qn + (size_t)row * E_ + pi_pos(tid * 8)) = pk;
  }
}

// ---------------- GEMM C[M,N] = A[M,K] @ B[N,K]^T (fp8 in/out, MX-rate) ----------------
// [r19/r20 verified: MX K=128 unit-scale, absmax unchanged]
__global__ __launch_bounds__(256) void gemm_qproj(
    const unsigned char* __restrict__ A, const unsigned char* __restrict__ B,
    unsigned char* __restrict__ C, int M, int N, int K)
{
  __shared__ __align__(16) unsigned char As[128 * 128];  // 16KB
  __shared__ __align__(16) unsigned char Bs[128 * 128];  // 16KB
  const int nwg = gridDim.x;
  const int cpx = nwg >> 3;
  const int swz = (blockIdx.x & 7) * cpx + (blockIdx.x >> 3);
  const int mt = M >> 7;
  const int bm = (swz % mt) * 128;
  const int bn = (swz / mt) * 128;
  const int tid = threadIdx.x;
  const int wave = tid >> 6, lane = tid & 63;
  const int r = lane & 15, g = lane >> 4;
  const int wm = (wave >> 1) * 64, wn = (wave & 1) * 64;
  const int fx = (r & 7) << 4;

  f32x4 acc[4][4] = {};

  for (int k0 = 0; k0 < K; k0 += 128) {
    #pragma unroll
    for (int c = 0; c < 4; ++c) {
      int chunk = wave * 4 + c;
      int off = chunk * 1024 + lane * 16;
      int row = off >> 7;
      int cb = (off & 127) ^ ((row & 7) << 4);
      gload_lds16(A + (size_t)(bm + row) * K + k0 + cb, (char*)As + chunk * 1024);
      gload_lds16(B + (size_t)(bn + row) * K + k0 + cb, (char*)Bs + chunk * 1024);
    }
    __syncthreads();
    {
      U32x8 af[4], bf[4];
      #pragma unroll
      for (int m = 0; m < 4; ++m) {
        const char* pr = (const char*)As + (wm + m * 16 + r) * 128;
        af[m].u2[0] = *(const ull2*)(pr + ((g * 32) ^ fx));
        af[m].u2[1] = *(const ull2*)(pr + ((g * 32 + 16) ^ fx));
      }
      #pragma unroll
      for (int n = 0; n < 4; ++n) {
        const char* pr = (const char*)Bs + (wn + n * 16 + r) * 128;
        bf[n].u2[0] = *(const ull2*)(pr + ((g * 32) ^ fx));
        bf[n].u2[1] = *(const ull2*)(pr + ((g * 32 + 16) ^ fx));
      }
      #pragma unroll
      for (int m = 0; m < 4; ++m)
        #pragma unroll
        for (int n = 0; n < 4; ++n)
          acc[m][n] = MFMAS(af[m].v, bf[n].v, acc[m][n]);
    }
    __syncthreads();
  }
  #pragma unroll
  for (int m = 0; m < 4; ++m)
    #pragma unroll
    for (int n = 0; n < 4; ++n)
      #pragma unroll
      for (int i = 0; i < 4; ++i) {
        int row = bm + wm + m * 16 + g * 4 + i;
        int col = bn + wn + n * 16 + r;
        C[(size_t)row * N + col] = f2e8(acc[m][n][i]);
      }
}

// ---------------- flash attention (fp8, MX-rate, 32 q-rows/wave) ----------------
// grid: (S/128, H, B); block 256 (4 waves x 32 q-rows); KVBLK=128; dbuf 80KB.
// Two q-fragments per wave (rows wave*16+r and +64): each K/V b128 feeds 2
// MFMAS -> per-CU LDS issue halves (r20's measured floor). Q loads use the
// VERIFIED plain layout (kc*32+g*8, r14-r20) — fixing r16's mis-pairing.
// Per-q-row math identical to r20 (MFMAS unit-scale, exp2, l-ones).
__global__ __launch_bounds__(256, 2) void attn_kernel(
    const unsigned char* __restrict__ q,    // [B*S][E] e4m3 (plain cols)
    const unsigned char* __restrict__ kb,   // [H][M][D] e4m3 (x32, pi-permuted d)
    const unsigned char* __restrict__ vtb,  // [H][D][M] e4m3 (x32, pi-permuted m%128)
    const float* __restrict__ beta,
    unsigned short* __restrict__ ret)       // [B*S][E] bf16
{
  __shared__ __align__(16) unsigned char Ks[2][128 * 128];  // 2 x 16KB
  __shared__ __align__(16) unsigned char Vs[2][128 * 128];  // 2 x 16KB
  __shared__ __align__(16) unsigned char Ps[4][32 * 128];   // 16KB
  const int s0 = blockIdx.x * 128;
  const int h = blockIdx.y;
  const int b = blockIdx.z;
  const int tid = threadIdx.x, wave = tid >> 6, lane = tid & 63;
  const int r = lane & 15, g = lane >> 4;
  const int fx = (r & 7) << 4;
  const float escale = beta[h] * (0.08838834764831845f * 1.4426950408889634f / 32.0f);

  // Q fragments: rows wave*16+r and +64, plain verified layout (kc*32+g*8)
  U32x8 qv0, qv1;
  {
    const unsigned char* qr0 =
        q + ((size_t)(b * S_) + s0 + wave * 16 + r) * E_ + h * D_;
    const unsigned char* qr1 = qr0 + (size_t)64 * E_;
    #pragma unroll
    for (int kc = 0; kc < 4; ++kc) {
      qv0.q[kc] = *(const long long*)(qr0 + kc * 32 + g * 8);
      qv1.q[kc] = *(const long long*)(qr1 + kc * 32 + g * 8);
    }
  }

  const unsigned char* Kh = kb + (size_t)h * M_ * D_;
  const unsigned char* Vh = vtb + (size_t)h * D_ * M_;
  unsigned char* Pw = Ps[wave];
  U32x8 ones8;
  #pragma unroll
  for (int i = 0; i < 4; ++i) ones8.q[i] = 0x3838383838383838LL;  // e4m3 1.0

  f32x4 o0[8] = {}, o1[8] = {};
  f32x4 ol0 = {}, ol1 = {};

  auto stage = [&](int buf, int m0) {
    #pragma unroll
    for (int c = 0; c < 4; ++c) {
      int chunk = wave * 4 + c;           // 16 x 1KB chunks per 16KB tile
      int off = chunk * 1024 + lane * 16;
      int row = off >> 7;                 // 128B rows
      int cb = (off & 127) ^ ((row & 7) << 4);
      gload_lds16(Kh + (size_t)(m0 + row) * 128 + cb, (char*)Ks[buf] + chunk * 1024);
      gload_lds16(Vh + (size_t)row * M_ + m0 + cb, (char*)Vs[buf] + chunk * 1024);
    }
  };

  stage(0, 0);
  __syncthreads();

  int cur = 0;
  for (int t = 0; t < M_ / 128; ++t) {
    if (t + 1 < M_ / 128) stage(cur ^ 1, (t + 1) * 128);

    const unsigned char* Kc = Ks[cur];
    const unsigned char* Vc = Vs[cur];

    // ---- S^T = K @ Q^T for both q-frags (K b128 reads shared)
    f32x4 sA[8] = {}, sB[8] = {};
    __builtin_amdgcn_s_setprio(1);
    #pragma unroll
    for (int nf = 0; nf < 8; ++nf) {
      const unsigned char* kr = Kc + (nf * 16 + r) * 128;
      U32x8 kf;
      kf.u2[0] = *(const ull2*)(kr + ((g * 32) ^ fx));
      kf.u2[1] = *(const ull2*)(kr + ((g * 32 + 16) ^ fx));
      sA[nf] = MFMAS(kf.v, qv0.v, sA[nf]);
      sB[nf] = MFMAS(kf.v, qv1.v, sB[nf]);
    }
    __builtin_amdgcn_s_setprio(0);

    // ---- P = 2^(s*escale) for both frags; packed e4m3 b32 writes
    #pragma unroll
    for (int nf = 0; nf < 8; ++nf) {
      int pbase = ((nf & 1) * 2 + (g >> 1)) * 32 + (nf >> 1) * 8 + (g & 1) * 4;
      {
        float p0 = exp2a(sA[nf][0] * escale), p1 = exp2a(sA[nf][1] * escale),
              p2 = exp2a(sA[nf][2] * escale), p3 = exp2a(sA[nf][3] * escale);
        *(uint32_t*)(Pw + r * 128 + (pbase ^ fx)) = pk4e8(p0, p1, p2, p3);
      }
      {
        float p0 = exp2a(sB[nf][0] * escale), p1 = exp2a(sB[nf][1] * escale),
              p2 = exp2a(sB[nf][2] * escale), p3 = exp2a(sB[nf][3] * escale);
        *(uint32_t*)(Pw + (16 + r) * 128 + (pbase ^ fx)) = pk4e8(p0, p1, p2, p3);
      }
    }

    // ---- O += P @ V ; l += P @ ones  (V b128 reads shared across frags)
    U32x8 pv0, pv1;
    pv0.u2[0] = *(const ull2*)(Pw + r * 128 + ((g * 32) ^ fx));
    pv0.u2[1] = *(const ull2*)(Pw + r * 128 + ((g * 32 + 16) ^ fx));
    pv1.u2[0] = *(const ull2*)(Pw + (16 + r) * 128 + ((g * 32) ^ fx));
    pv1.u2[1] = *(const ull2*)(Pw + (16 + r) * 128 + ((g * 32 + 16) ^ fx));
    __builtin_amdgcn_s_setprio(1);
    ol0 = MFMAS(pv0.v, ones8.v, ol0);
    ol1 = MFMAS(pv1.v, ones8.v, ol1);
    #pragma unroll
    for (int nf2 = 0; nf2 < 8; ++nf2) {
      const unsigned char* vr = Vc + (nf2 * 16 + r) * 128;
      U32x8 vf;
      vf.u2[0] = *(const ull2*)(vr + ((g * 32) ^ fx));
      vf.u2[1] = *(const ull2*)(vr + ((g * 32 + 16) ^ fx));
      o0[nf2] = MFMAS(pv0.v, vf.v, o0[nf2]);
      o1[nf2] = MFMAS(pv1.v, vf.v, o1[nf2]);
    }
    __builtin_amdgcn_s_setprio(0);
    __syncthreads();
    cur ^= 1;
  }

  // ---- epilogue: retrieved = (O_enc / l) / 32 ; no cross-lane needed
  {
    float inv[4];
    #pragma unroll
    for (int i = 0; i < 4; ++i) inv[i] = 0.03125f / ol0[i];
    unsigned short* rr = ret + ((size_t)(b * S_) + s0 + wave * 16) * E_ + h * D_;
    #pragma unroll
    for (int nf2 = 0; nf2 < 8; ++nf2)
      #pragma unroll
      for (int i = 0; i < 4; ++i)
        rr[(size_t)(g * 4 + i) * E_ + nf2 * 16 + r] = f2bf(o0[nf2][i] * inv[i]);
  }
  {
    float inv[4];
    #pragma unroll
    for (int i = 0; i < 4; ++i) inv[i] = 0.03125f / ol1[i];
    unsigned short* rr = ret + ((size_t)(b * S_) + s0 + 64 + wave * 16) * E_ + h * D_;
    #pragma unroll
    for (int nf2 = 0; nf2 < 8; ++nf2)
      #pragma unroll
      for (int i = 0; i < 4; ++i)
        rr[(size_t)(g * 4 + i) * E_ + nf2 * 16 + r] = f2bf(o1[nf2][i] * inv[i]);
  }
}

// ---------------- final: out = query + rmsnorm(retrieved)*w ----------------
__global__ __launch_bounds__(256) void final_kernel(
    const unsigned short* __restrict__ ret, const float* __restrict__ w,
    const float* __restrict__ query, float* __restrict__ out)
{
  const int row = blockIdx.x;
  const int tid = threadIdx.x;
  u16x8 hv = *(const u16x8*)(ret + (size_t)row * E_ + tid * 8);
  float x[8];
  float ss = 0.f;
  #pragma unroll
  for (int j = 0; j < 8; ++j) { x[j] = bf2f(hv[j]); ss += x[j] * x[j]; }
  float tot = block_sum(ss);
  float sc = rsqrtf(tot * (1.0f / E_) + 1e-5f);
  const float* qr = query + (size_t)row * E_ + tid * 8;
  const float* wr = w + tid * 8;
  float o[8];
  #pragma unroll
  for (int j = 0; j < 8; ++j) o[j] = qr[j] + x[j] * sc * wr[j];
  float4* op = (float4*)(out + (size_t)row * E_ + tid * 8);
  op[0] = make_float4(o[0], o[1], o[2], o[3]);
  op[1] = make_float4(o[4], o[5], o[6], o[7]);
}

extern "C" void kernel_launch(void* const* d_in, const int* in_sizes, int n_in,
                              void* d_out, int out_size, void* d_ws, size_t ws_size,
                              hipStream_t stream) {
  const float* query = (const float*)d_in[0];
  const float* sp    = (const float*)d_in[1];
  const float* wq    = (const float*)d_in[2];
  const float* wk    = (const float*)d_in[3];
  const float* wv    = (const float*)d_in[4];
  const float* beta  = (const float*)d_in[5];
  const float* nqw   = (const float*)d_in[6];
  const float* nrw   = (const float*)d_in[7];
  float* out = (float*)d_out;

  char* ws = (char*)d_ws;
  unsigned char*  wqb = (unsigned char*)(ws + 0);                     // 4 MB (fp8)
  unsigned char*  qn  = (unsigned char*)(ws + ((size_t)8 << 20));     // 8 MB (fp8)
  unsigned char*  qb  = (unsigned char*)(ws + ((size_t)24 << 20));    // 8 MB (fp8)
  unsigned char*  kb  = (unsigned char*)(ws + ((size_t)32 << 20));    // 4 MB (fp8)
  unsigned char*  vtb = (unsigned char*)(ws + ((size_t)36 << 20));    // 4 MB (fp8)
  unsigned short* ret = (unsigned short*)(ws + ((size_t)40 << 20));   // 16 MB (bf16)

  prep_kernel<<<PREP_PROJ + PREP_CONV + PREP_NORM, 256, 0, stream>>>(
      query, sp, wq, wk, wv, nqw, wqb, qn, kb, vtb);
  gemm_qproj<<<(B_ * S_ / 128) * (E_ / 128), 256, 0, stream>>>(
      qn, wqb, qb, B_ * S_, E_, E_);
  attn_kernel<<<dim3(S_ / 128, H_, B_), 256, 0, stream>>>(qb, kb, vtb, beta, ret);
  final_kernel<<<B_ * S_, 256, 0, stream>>>(ret, nrw, query, out);
}

// Round 22
// 116.538 us; speedup vs baseline: 1.1514x; 1.0307x over previous
//
#include <hip/hip_runtime.h>
#include <hip/hip_bf16.h>
#include <stdint.h>

typedef __attribute__((ext_vector_type(8))) short bf16x8;
typedef __attribute__((ext_vector_type(4))) float f32x4;
typedef __attribute__((ext_vector_type(8))) unsigned short u16x8;
typedef __attribute__((ext_vector_type(4))) unsigned short u16x4;
typedef __attribute__((ext_vector_type(2))) unsigned long long ull2;
typedef __attribute__((ext_vector_type(8))) int i32x8;

#define B_ 2
#define S_ 2048
#define E_ 2048
#define H_ 16
#define M_ 2048
#define D_ 128

#define MFMA16(a, b, c) __builtin_amdgcn_mfma_f32_16x16x32_bf16(a, b, c, 0, 0, 0)
#define MFMA8(a, b, c) __builtin_amdgcn_mfma_f32_16x16x32_fp8_fp8(a, b, c, 0, 0, 0)
// MX-scaled fp8, K=128, unit scales (e8m0 127 = 2^0): plain fp8 math at 2x rate
#define MFMAS(a, b, c) __builtin_amdgcn_mfma_scale_f32_16x16x128_f8f6f4( \
    a, b, c, 0, 0, 0, 127, 0, 127)

union U32x8 { ull2 u2[2]; long long q[4]; i32x8 v; };

__device__ inline unsigned short f2bf(float f) {
  union { float f; unsigned u; } v; v.f = f;
  unsigned r = v.u + 0x7FFFu + ((v.u >> 16) & 1u);
  return (unsigned short)(r >> 16);
}
__device__ inline float bf2f(unsigned short h) {
  union { unsigned u; float f; } v; v.u = ((unsigned)h) << 16;
  return v.f;
}

// f32 -> e4m3 single byte via HW converter (branch-free; verified r12-r21)
__device__ inline unsigned char f2e8(float f) {
  return (unsigned char)(__builtin_amdgcn_cvt_pk_fp8_f32(f, f, 0, false) & 0xFF);
}
// 4 floats -> 4 packed e4m3 bytes (verified pattern)
__device__ inline uint32_t pk4e8(float a, float b, float c, float d) {
  uint32_t w = 0;
  w = (uint32_t)__builtin_amdgcn_cvt_pk_fp8_f32(a, b, (int)w, false);
  w = (uint32_t)__builtin_amdgcn_cvt_pk_fp8_f32(c, d, (int)w, true);
  return w;
}

// native 2^x
__device__ inline float exp2a(float x) {
  float r;
  asm("v_exp_f32 %0, %1" : "=v"(r) : "v"(x));
  return r;
}

__device__ inline void gload_lds16(const void* g, void* l) {
  __builtin_amdgcn_global_load_lds(
      (__attribute__((address_space(1))) void*)g,
      (__attribute__((address_space(3))) void*)l, 16, 0, 0);
}

__device__ inline bf16x8 pack8(float4 f0, float4 f1) {
  bf16x8 o;
  o[0] = (short)f2bf(f0.x); o[1] = (short)f2bf(f0.y);
  o[2] = (short)f2bf(f0.z); o[3] = (short)f2bf(f0.w);
  o[4] = (short)f2bf(f1.x); o[5] = (short)f2bf(f1.y);
  o[6] = (short)f2bf(f1.z); o[7] = (short)f2bf(f1.w);
  return o;
}

__device__ inline float block_sum(float v) {
  __shared__ float red[4];
  #pragma unroll
  for (int o = 32; o > 0; o >>= 1) v += __shfl_xor(v, o);
  int tid = threadIdx.x;
  if ((tid & 63) == 0) red[tid >> 6] = v;
  __syncthreads();
  return red[0] + red[1] + red[2] + red[3];
}

// pi(col) within a 128-col group: bits[6:5] <-> [4:3]  (col%8 preserved)
__device__ inline int pi_pos(int c) {
  return (c & ~127) | (((c >> 3) & 3) * 32) | (((c >> 5) & 3) * 8) | (c & 7);
}

// ---------------- prep: wq->fp8 | rmsnorm(q)->fp8 (both pure-BW) ----------------
#define PREP_CONV 2048
#define PREP_NORM 4096
__global__ __launch_bounds__(256) void prep_kernel(
    const float* __restrict__ query, const float* __restrict__ wq,
    const float* __restrict__ nqw,
    unsigned char* __restrict__ wqb, unsigned char* __restrict__ qn)
{
  const int bid = blockIdx.x;
  const int tid = threadIdx.x;

  if (bid < PREP_CONV) {
    // ---- wq: f32 -> fp8 pi-permuted
    int i = bid * 256 + tid;
    const float* p = wq + (size_t)i * 8;
    float4 a = *(const float4*)p, b = *(const float4*)(p + 4);
    uint2 pk;
    pk.x = pk4e8(a.x, a.y, a.z, a.w);
    pk.y = pk4e8(b.x, b.y, b.z, b.w);
    size_t flat = (size_t)i * 8;
    int c = (int)(flat & (E_ - 1));
    *(uint2*)(wqb + (flat - c) + pi_pos(c)) = pk;
  } else {
    // ---- RMSNorm(query) -> fp8 qn (pi-permuted)
    const int row = bid - PREP_CONV;
    const float* xr = query + (size_t)row * E_;
    float4 v0 = ((const float4*)xr)[tid * 2];
    float4 v1 = ((const float4*)xr)[tid * 2 + 1];
    float ss = v0.x*v0.x + v0.y*v0.y + v0.z*v0.z + v0.w*v0.w
             + v1.x*v1.x + v1.y*v1.y + v1.z*v1.z + v1.w*v1.w;
    float tot = block_sum(ss);
    float sc = rsqrtf(tot * (1.0f / E_) + 1e-5f);
    float vals[8] = {v0.x, v0.y, v0.z, v0.w, v1.x, v1.y, v1.z, v1.w};
    const float* wr = nqw + tid * 8;
    float f[8];
    #pragma unroll
    for (int j = 0; j < 8; ++j) f[j] = vals[j] * sc * wr[j];
    uint2 pk;
    pk.x = pk4e8(f[0], f[1], f[2], f[3]);
    pk.y = pk4e8(f[4], f[5], f[6], f[7]);
    *(uint2*)(qn + (size_t)row * E_ + pi_pos(tid * 8)) = pk;
  }
}

// ---------------- fused: q-GEMM (512 blocks) || proj_kv (512 blocks) ----------------
// Independent workloads with complementary bottlenecks (gemm: LDS/MFMA-bound;
// proj: global-latency-bound) -> one launch overlaps them on the CUs.
// Bodies byte-identical to r19-r21 verified kernels; gemm swizzle uses the
// literal block count (512), not gridDim.
#define GEMM_WG 512
__global__ __launch_bounds__(256) void gemm_proj_kernel(
    const unsigned char* __restrict__ A, const unsigned char* __restrict__ Bm,
    unsigned char* __restrict__ C,
    const float* __restrict__ sp, const float* __restrict__ wk,
    const float* __restrict__ wv,
    unsigned char* __restrict__ kout, unsigned char* __restrict__ vtout)
{
  __shared__ __align__(16) unsigned char As[128 * 128];  // 16KB
  __shared__ __align__(16) unsigned char Bs[128 * 128];  // 16KB
  const int tid = threadIdx.x;
  const int wave = tid >> 6, lane = tid & 63;
  const int r = lane & 15, g = lane >> 4;
  const int fx = (r & 7) << 4;

  if (blockIdx.x < GEMM_WG) {
    // ================= q-GEMM: C[M,N] = A @ B^T (fp8, MX-rate) =================
    const int M = B_ * S_, N = E_, K = E_;
    const int cpx = GEMM_WG >> 3;
    const int swz = (blockIdx.x & 7) * cpx + (blockIdx.x >> 3);
    const int mt = M >> 7;
    const int bm = (swz % mt) * 128;
    const int bn = (swz / mt) * 128;
    const int wm = (wave >> 1) * 64, wn = (wave & 1) * 64;

    f32x4 acc[4][4] = {};

    for (int k0 = 0; k0 < K; k0 += 128) {
      #pragma unroll
      for (int c = 0; c < 4; ++c) {
        int chunk = wave * 4 + c;
        int off = chunk * 1024 + lane * 16;
        int row = off >> 7;
        int cb = (off & 127) ^ ((row & 7) << 4);
        gload_lds16(A + (size_t)(bm + row) * K + k0 + cb, (char*)As + chunk * 1024);
        gload_lds16(Bm + (size_t)(bn + row) * K + k0 + cb, (char*)Bs + chunk * 1024);
      }
      __syncthreads();
      {
        U32x8 af[4], bf[4];
        #pragma unroll
        for (int m = 0; m < 4; ++m) {
          const char* pr = (const char*)As + (wm + m * 16 + r) * 128;
          af[m].u2[0] = *(const ull2*)(pr + ((g * 32) ^ fx));
          af[m].u2[1] = *(const ull2*)(pr + ((g * 32 + 16) ^ fx));
        }
        #pragma unroll
        for (int n = 0; n < 4; ++n) {
          const char* pr = (const char*)Bs + (wn + n * 16 + r) * 128;
          bf[n].u2[0] = *(const ull2*)(pr + ((g * 32) ^ fx));
          bf[n].u2[1] = *(const ull2*)(pr + ((g * 32 + 16) ^ fx));
        }
        #pragma unroll
        for (int m = 0; m < 4; ++m)
          #pragma unroll
          for (int n = 0; n < 4; ++n)
            acc[m][n] = MFMAS(af[m].v, bf[n].v, acc[m][n]);
      }
      __syncthreads();
    }
    #pragma unroll
    for (int m = 0; m < 4; ++m)
      #pragma unroll
      for (int n = 0; n < 4; ++n)
        #pragma unroll
        for (int i = 0; i < 4; ++i) {
          int row = bm + wm + m * 16 + g * 4 + i;
          int col = bn + wn + n * 16 + r;
          C[(size_t)row * N + col] = f2e8(acc[m][n][i]);
        }
  } else {
    // ================= proj_kv: fused K/V projections (fp8, x32, pi) ============
    const int idx = blockIdx.x - GEMM_WG;
    const int m0 = (idx & 31) * 64;
    const int h = idx >> 5;
    const int wm = (wave >> 1) * 32, wn = (wave & 1) * 64;
    const float* spb = sp + ((size_t)h * M_ + m0) * D_;
    f32x4 acck[2][4] = {};
    f32x4 accv[2][4] = {};
    #pragma unroll
    for (int kc = 0; kc < 4; ++kc) {
      bf16x8 a[2], bk[4], bv[4];
      #pragma unroll
      for (int m = 0; m < 2; ++m) {
        const float* p = spb + (size_t)(wm + m * 16 + r) * D_ + kc * 32 + g * 8;
        a[m] = pack8(*(const float4*)p, *(const float4*)(p + 4));
      }
      #pragma unroll
      for (int n = 0; n < 4; ++n) {
        const float* pk = wk + (size_t)(wn + n * 16 + r) * D_ + kc * 32 + g * 8;
        bk[n] = pack8(*(const float4*)pk, *(const float4*)(pk + 4));
        const float* pv = wv + (size_t)(wn + n * 16 + r) * D_ + kc * 32 + g * 8;
        bv[n] = pack8(*(const float4*)pv, *(const float4*)(pv + 4));
      }
      #pragma unroll
      for (int m = 0; m < 2; ++m)
        #pragma unroll
        for (int n = 0; n < 4; ++n) {
          acck[m][n] = MFMA16(a[m], bk[n], acck[m][n]);
          accv[m][n] = MFMA16(a[m], bv[n], accv[m][n]);
        }
    }
    #pragma unroll
    for (int m = 0; m < 2; ++m)
      #pragma unroll
      for (int n = 0; n < 4; ++n)
        #pragma unroll
        for (int i = 0; i < 4; ++i) {
          int d = wn + n * 16 + r;
          kout[((size_t)h * M_ + m0 + wm + m * 16 + g * 4 + i) * D_ + pi_pos(d)]
              = f2e8(acck[m][n][i] * 32.0f);
          int mc = m0 + wm + m * 16 + g * 4 + i;
          int mp = (mc & ~127) | (pi_pos(mc & 127));
          vtout[((size_t)h * D_ + wn + n * 16 + r) * M_ + mp]
              = f2e8(accv[m][n][i] * 32.0f);
        }
  }
}

// ---------------- flash attention (fp8, MX-rate, 32 q-rows/wave) ----------------
// [r21 verified: 57.3us, absmax 0.046875 — byte-identical]
__global__ __launch_bounds__(256, 2) void attn_kernel(
    const unsigned char* __restrict__ q,    // [B*S][E] e4m3 (plain cols)
    const unsigned char* __restrict__ kb,   // [H][M][D] e4m3 (x32, pi-permuted d)
    const unsigned char* __restrict__ vtb,  // [H][D][M] e4m3 (x32, pi-permuted m%128)
    const float* __restrict__ beta,
    unsigned short* __restrict__ ret)       // [B*S][E] bf16
{
  __shared__ __align__(16) unsigned char Ks[2][128 * 128];  // 2 x 16KB
  __shared__ __align__(16) unsigned char Vs[2][128 * 128];  // 2 x 16KB
  __shared__ __align__(16) unsigned char Ps[4][32 * 128];   // 16KB
  const int s0 = blockIdx.x * 128;
  const int h = blockIdx.y;
  const int b = blockIdx.z;
  const int tid = threadIdx.x, wave = tid >> 6, lane = tid & 63;
  const int r = lane & 15, g = lane >> 4;
  const int fx = (r & 7) << 4;
  const float escale = beta[h] * (0.08838834764831845f * 1.4426950408889634f / 32.0f);

  U32x8 qv0, qv1;
  {
    const unsigned char* qr0 =
        q + ((size_t)(b * S_) + s0 + wave * 16 + r) * E_ + h * D_;
    const unsigned char* qr1 = qr0 + (size_t)64 * E_;
    #pragma unroll
    for (int kc = 0; kc < 4; ++kc) {
      qv0.q[kc] = *(const long long*)(qr0 + kc * 32 + g * 8);
      qv1.q[kc] = *(const long long*)(qr1 + kc * 32 + g * 8);
    }
  }

  const unsigned char* Kh = kb + (size_t)h * M_ * D_;
  const unsigned char* Vh = vtb + (size_t)h * D_ * M_;
  unsigned char* Pw = Ps[wave];
  U32x8 ones8;
  #pragma unroll
  for (int i = 0; i < 4; ++i) ones8.q[i] = 0x3838383838383838LL;  // e4m3 1.0

  f32x4 o0[8] = {}, o1[8] = {};
  f32x4 ol0 = {}, ol1 = {};

  auto stage = [&](int buf, int m0) {
    #pragma unroll
    for (int c = 0; c < 4; ++c) {
      int chunk = wave * 4 + c;
      int off = chunk * 1024 + lane * 16;
      int row = off >> 7;
      int cb = (off & 127) ^ ((row & 7) << 4);
      gload_lds16(Kh + (size_t)(m0 + row) * 128 + cb, (char*)Ks[buf] + chunk * 1024);
      gload_lds16(Vh + (size_t)row * M_ + m0 + cb, (char*)Vs[buf] + chunk * 1024);
    }
  };

  stage(0, 0);
  __syncthreads();

  int cur = 0;
  for (int t = 0; t < M_ / 128; ++t) {
    if (t + 1 < M_ / 128) stage(cur ^ 1, (t + 1) * 128);

    const unsigned char* Kc = Ks[cur];
    const unsigned char* Vc = Vs[cur];

    f32x4 sA[8] = {}, sB[8] = {};
    __builtin_amdgcn_s_setprio(1);
    #pragma unroll
    for (int nf = 0; nf < 8; ++nf) {
      const unsigned char* kr = Kc + (nf * 16 + r) * 128;
      U32x8 kf;
      kf.u2[0] = *(const ull2*)(kr + ((g * 32) ^ fx));
      kf.u2[1] = *(const ull2*)(kr + ((g * 32 + 16) ^ fx));
      sA[nf] = MFMAS(kf.v, qv0.v, sA[nf]);
      sB[nf] = MFMAS(kf.v, qv1.v, sB[nf]);
    }
    __builtin_amdgcn_s_setprio(0);

    #pragma unroll
    for (int nf = 0; nf < 8; ++nf) {
      int pbase = ((nf & 1) * 2 + (g >> 1)) * 32 + (nf >> 1) * 8 + (g & 1) * 4;
      {
        float p0 = exp2a(sA[nf][0] * escale), p1 = exp2a(sA[nf][1] * escale),
              p2 = exp2a(sA[nf][2] * escale), p3 = exp2a(sA[nf][3] * escale);
        *(uint32_t*)(Pw + r * 128 + (pbase ^ fx)) = pk4e8(p0, p1, p2, p3);
      }
      {
        float p0 = exp2a(sB[nf][0] * escale), p1 = exp2a(sB[nf][1] * escale),
              p2 = exp2a(sB[nf][2] * escale), p3 = exp2a(sB[nf][3] * escale);
        *(uint32_t*)(Pw + (16 + r) * 128 + (pbase ^ fx)) = pk4e8(p0, p1, p2, p3);
      }
    }

    U32x8 pv0, pv1;
    pv0.u2[0] = *(const ull2*)(Pw + r * 128 + ((g * 32) ^ fx));
    pv0.u2[1] = *(const ull2*)(Pw + r * 128 + ((g * 32 + 16) ^ fx));
    pv1.u2[0] = *(const ull2*)(Pw + (16 + r) * 128 + ((g * 32) ^ fx));
    pv1.u2[1] = *(const ull2*)(Pw + (16 + r) * 128 + ((g * 32 + 16) ^ fx));
    __builtin_amdgcn_s_setprio(1);
    ol0 = MFMAS(pv0.v, ones8.v, ol0);
    ol1 = MFMAS(pv1.v, ones8.v, ol1);
    #pragma unroll
    for (int nf2 = 0; nf2 < 8; ++nf2) {
      const unsigned char* vr = Vc + (nf2 * 16 + r) * 128;
      U32x8 vf;
      vf.u2[0] = *(const ull2*)(vr + ((g * 32) ^ fx));
      vf.u2[1] = *(const ull2*)(vr + ((g * 32 + 16) ^ fx));
      o0[nf2] = MFMAS(pv0.v, vf.v, o0[nf2]);
      o1[nf2] = MFMAS(pv1.v, vf.v, o1[nf2]);
    }
    __builtin_amdgcn_s_setprio(0);
    __syncthreads();
    cur ^= 1;
  }

  {
    float inv[4];
    #pragma unroll
    for (int i = 0; i < 4; ++i) inv[i] = 0.03125f / ol0[i];
    unsigned short* rr = ret + ((size_t)(b * S_) + s0 + wave * 16) * E_ + h * D_;
    #pragma unroll
    for (int nf2 = 0; nf2 < 8; ++nf2)
      #pragma unroll
      for (int i = 0; i < 4; ++i)
        rr[(size_t)(g * 4 + i) * E_ + nf2 * 16 + r] = f2bf(o0[nf2][i] * inv[i]);
  }
  {
    float inv[4];
    #pragma unroll
    for (int i = 0; i < 4; ++i) inv[i] = 0.03125f / ol1[i];
    unsigned short* rr = ret + ((size_t)(b * S_) + s0 + 64 + wave * 16) * E_ + h * D_;
    #pragma unroll
    for (int nf2 = 0; nf2 < 8; ++nf2)
      #pragma unroll
      for (int i = 0; i < 4; ++i)
        rr[(size_t)(g * 4 + i) * E_ + nf2 * 16 + r] = f2bf(o1[nf2][i] * inv[i]);
  }
}

// ---------------- final: out = query + rmsnorm(retrieved)*w ----------------
__global__ __launch_bounds__(256) void final_kernel(
    const unsigned short* __restrict__ ret, const float* __restrict__ w,
    const float* __restrict__ query, float* __restrict__ out)
{
  const int row = blockIdx.x;
  const int tid = threadIdx.x;
  u16x8 hv = *(const u16x8*)(ret + (size_t)row * E_ + tid * 8);
  float x[8];
  float ss = 0.f;
  #pragma unroll
  for (int j = 0; j < 8; ++j) { x[j] = bf2f(hv[j]); ss += x[j] * x[j]; }
  float tot = block_sum(ss);
  float sc = rsqrtf(tot * (1.0f / E_) + 1e-5f);
  const float* qr = query + (size_t)row * E_ + tid * 8;
  const float* wr = w + tid * 8;
  float o[8];
  #pragma unroll
  for (int j = 0; j < 8; ++j) o[j] = qr[j] + x[j] * sc * wr[j];
  float4* op = (float4*)(out + (size_t)row * E_ + tid * 8);
  op[0] = make_float4(o[0], o[1], o[2], o[3]);
  op[1] = make_float4(o[4], o[5], o[6], o[7]);
}

extern "C" void kernel_launch(void* const* d_in, const int* in_sizes, int n_in,
                              void* d_out, int out_size, void* d_ws, size_t ws_size,
                              hipStream_t stream) {
  const float* query = (const float*)d_in[0];
  const float* sp    = (const float*)d_in[1];
  const float* wq    = (const float*)d_in[2];
  const float* wk    = (const float*)d_in[3];
  const float* wv    = (const float*)d_in[4];
  const float* beta  = (const float*)d_in[5];
  const float* nqw   = (const float*)d_in[6];
  const float* nrw   = (const float*)d_in[7];
  float* out = (float*)d_out;

  char* ws = (char*)d_ws;
  unsigned char*  wqb = (unsigned char*)(ws + 0);                     // 4 MB (fp8)
  unsigned char*  qn  = (unsigned char*)(ws + ((size_t)8 << 20));     // 8 MB (fp8)
  unsigned char*  qb  = (unsigned char*)(ws + ((size_t)24 << 20));    // 8 MB (fp8)
  unsigned char*  kb  = (unsigned char*)(ws + ((size_t)32 << 20));    // 4 MB (fp8)
  unsigned char*  vtb = (unsigned char*)(ws + ((size_t)36 << 20));    // 4 MB (fp8)
  unsigned short* ret = (unsigned short*)(ws + ((size_t)40 << 20));   // 16 MB (bf16)

  prep_kernel<<<PREP_CONV + PREP_NORM, 256, 0, stream>>>(query, wq, nqw, wqb, qn);
  gemm_proj_kernel<<<GEMM_WG + 512, 256, 0, stream>>>(
      qn, wqb, qb, sp, wk, wv, kb, vtb);
  attn_kernel<<<dim3(S_ / 128, H_, B_), 256, 0, stream>>>(qb, kb, vtb, beta, ret);
  final_kernel<<<B_ * S_, 256, 0, stream>>>(ret, nrw, query, out);
}